// Round 3
// baseline (655.937 us; speedup 1.0000x reference)
//
#include <hip/hip_runtime.h>

typedef __attribute__((ext_vector_type(8))) short bf16x8;
typedef __attribute__((ext_vector_type(4))) float f32x4;

#define CCH 32   // chunks over L
#define TCH 64   // chunk length

// ---------- bf16 helpers (round-to-nearest-even) ----------
__device__ __forceinline__ unsigned short f2b(float f) {
    unsigned u = __float_as_uint(f);
    return (unsigned short)((u + 0x7fffu + ((u >> 16) & 1u)) >> 16);
}
__device__ __forceinline__ float b2f(unsigned short h) {
    return __uint_as_float(((unsigned)h) << 16);
}
__device__ __forceinline__ float softplus_f(float z) {
    return (z > 15.f) ? z : __logf(1.f + __expf(z));
}
__device__ __forceinline__ float silu_f(float g) {
    return g / (1.f + __expf(-g));
}

// async 16B/lane global->LDS (lds dst = wave-uniform base + lane*16)
__device__ __forceinline__ void gload16(const unsigned short* g, unsigned short* l) {
    __builtin_amdgcn_global_load_lds(
        (const __attribute__((address_space(1))) void*)g,
        (__attribute__((address_space(3))) void*)l, 16, 0, 0);
}

// ---------- fused fp32 -> bf16 cast for all 5 tensors ----------
__global__ __launch_bounds__(256)
void cast_all(const float* __restrict__ h, const float* __restrict__ win,
              const float* __restrict__ wx, const float* __restrict__ wdt,
              const float* __restrict__ wout,
              unsigned short* __restrict__ dh, unsigned short* __restrict__ dwin,
              unsigned short* __restrict__ dwx, unsigned short* __restrict__ dwdt,
              unsigned short* __restrict__ dwout) {
    const int n0 = 1572864, n1 = n0 + 2359296, n2 = n1 + 98304,
              n3 = n2 + 73728, n4 = n3 + 1179648;
    int i = blockIdx.x * 256 + threadIdx.x;
    const float* s; unsigned short* d; int off;
    if (i < n0)      { s = h;    d = dh;    off = i; }
    else if (i < n1) { s = win;  d = dwin;  off = i - n0; }
    else if (i < n2) { s = wx;   d = dwx;   off = i - n1; }
    else if (i < n3) { s = wdt;  d = dwdt;  off = i - n2; }
    else if (i < n4) { s = wout; d = dwout; off = i - n3; }
    else return;
    float4 v = reinterpret_cast<const float4*>(s)[off];
    ushort4 o;
    o.x = f2b(v.x); o.y = f2b(v.y); o.z = f2b(v.z); o.w = f2b(v.w);
    reinterpret_cast<ushort4*>(d)[off] = o;
}

// ============================================================================
// 256x256 GEMM, 4 phases/K-tile with REGISTER-PIPELINED fragment reads.
// C[M,N] = A[M,Kc] x W[N,Kc]^T, bf16, BK=64, 512 thr = 8 waves (2M x 4N).
// Phase p issues the ds_reads for phase p+1's quadrant, then MFMAs the
// quadrant whose fragments were read last phase -> LDS drain overlaps MFMA.
// No manual lgkmcnt: fragment reads are plain loads, hipcc emits counted
// lgkm waits that skip the just-issued next-phase reads.
// MFMA order (0,0)(1,0)(0,1)(1,1); reg sets faA/faB/fbA/fbB are each dead
// exactly one phase before their re-read.  Staging: uniform 2 gload/phase,
// tile t+1/t+2 halves, each LDS region overwritten >=1 barrier after its
// last consuming MFMA; uniform vmcnt(6) at phase end (4-phase issue->read
// distance); epilogue drains VM6/VM4/VM2/VM0 (deadlines hand-verified).
// Requires: Kc%128==0 (nkt even >=4), M%256==0, N%256==0, grid.x%8==0.
// OP=0: fp32 store (+ split-K kz, C offset kz*czs); OP=2: bf16, silu for
// col >= silu_col0.
// ============================================================================
template <int OP>
__global__ __launch_bounds__(512)
void gemm256(const unsigned short* __restrict__ A, const unsigned short* __restrict__ W,
             void* __restrict__ Cout, int Kc, int lda, int ldw, int ldc,
             int ntx, int nty, int silu_col0, long long czs) {
    __shared__ __align__(16) unsigned short lds[65536];   // A[2][16384] | B[2][16384]
    const int tid  = threadIdx.x;
    const int lane = tid & 63;
    const int wave = tid >> 6;
    const int wr   = wave >> 2;    // 0..1 (M)
    const int wc   = wave & 3;     // 0..3 (N)
    const int lr   = lane & 15;
    const int quad = lane >> 4;
    const int sw   = lr & 7;       // read-side XOR

    // XCD-local stripe mapping (bijective; grid.x % 8 == 0)
    const int c = blockIdx.x & 7;
    const int j = blockIdx.x >> 3;
    int bm_t, bn_t;
    if ((ntx & 7) == 0) {          // column stripes per XCD
        const int cpx = ntx >> 3;
        bn_t = c * cpx + j % cpx;
        bm_t = j / cpx;
    } else {                       // row stripes per XCD (nty % 8 == 0)
        const int rpx = nty >> 3;
        bm_t = c * rpx + j % rpx;
        bn_t = j / rpx;
    }
    const int bm = bm_t * 256;
    const int bn = bn_t * 256;
    const int kz = blockIdx.z;
    A += (size_t)kz * Kc;
    W += (size_t)kz * Kc;

    // staging: thread covers row (wave*8 + lane>>3) of each 64-row load op,
    // 16B slot (lane&7); global col pre-swizzled by row&7 = (lane>>3)&7.
    const int rsub = wave * 8 + (lane >> 3);
    const int csw  = ((lane & 7) ^ ((lane >> 3) & 7)) * 8;
    const unsigned short* gA = A + (size_t)(bm + rsub) * lda + csw;
    const unsigned short* gB = W + (size_t)(bn + rsub) * ldw + csw;

    // stage half h (128 rows), koff = bf16 col offset (64*tile_delta)
#define STA(b, h, koff) do { \
        gload16(gA + (size_t)((h) * 128) * lda + (koff),      &lds[(b) * 16384 + (h) * 8192 + wave * 512]); \
        gload16(gA + (size_t)((h) * 128 + 64) * lda + (koff), &lds[(b) * 16384 + (h) * 8192 + 4096 + wave * 512]); \
    } while (0)
#define STB(b, h, koff) do { \
        gload16(gB + (size_t)((h) * 128) * ldw + (koff),      &lds[32768 + (b) * 16384 + (h) * 8192 + wave * 512]); \
        gload16(gB + (size_t)((h) * 128 + 64) * ldw + (koff), &lds[32768 + (b) * 16384 + (h) * 8192 + 4096 + wave * 512]); \
    } while (0)

    // swizzled fragment reads (slot = (kk*4+quad) ^ (row&7), row&7 == lr&7)
#define LDA_F(b, mh, mi, kk) \
    (*reinterpret_cast<const bf16x8*>(&lds[(b) * 16384 + ((mh) * 128 + wr * 64 + (mi) * 16 + lr) * 64 + (((((kk) << 2) | quad)) ^ sw) * 8]))
#define LDB_F(b, nh, ni, kk) \
    (*reinterpret_cast<const bf16x8*>(&lds[32768 + (b) * 16384 + ((nh) * 128 + wc * 32 + (ni) * 16 + lr) * 64 + (((((kk) << 2) | quad)) ^ sw) * 8]))

#define RD_A(b, mh, DST) do { \
        _Pragma("unroll") for (int mi = 0; mi < 4; ++mi) { \
            DST[mi][0] = LDA_F(b, mh, mi, 0); \
            DST[mi][1] = LDA_F(b, mh, mi, 1); } } while (0)
#define RD_B(b, nh, DST) do { \
        _Pragma("unroll") for (int ni = 0; ni < 2; ++ni) { \
            DST[ni][0] = LDB_F(b, nh, ni, 0); \
            DST[ni][1] = LDB_F(b, nh, ni, 1); } } while (0)

#define MFMA_Q(mh, nh, FA, FB) do { \
        _Pragma("unroll") for (int mi = 0; mi < 4; ++mi) \
        _Pragma("unroll") for (int ni = 0; ni < 2; ++ni) { \
            acc[(mh) * 4 + mi][(nh) * 2 + ni] = __builtin_amdgcn_mfma_f32_16x16x32_bf16(FA[mi][0], FB[ni][0], acc[(mh) * 4 + mi][(nh) * 2 + ni], 0, 0, 0); \
            acc[(mh) * 4 + mi][(nh) * 2 + ni] = __builtin_amdgcn_mfma_f32_16x16x32_bf16(FA[mi][1], FB[ni][1], acc[(mh) * 4 + mi][(nh) * 2 + ni], 0, 0, 0); } } while (0)

#define MIDB  asm volatile("s_barrier" ::: "memory")
#define VM6B  asm volatile("s_waitcnt vmcnt(6)\n\ts_barrier" ::: "memory")
#define VM4B  asm volatile("s_waitcnt vmcnt(4)\n\ts_barrier" ::: "memory")
#define VM2B  asm volatile("s_waitcnt vmcnt(2)\n\ts_barrier" ::: "memory")
#define VM0B  asm volatile("s_waitcnt vmcnt(0)\n\ts_barrier" ::: "memory")
#define PRIO1 __builtin_amdgcn_s_setprio(1)
#define PRIO0 __builtin_amdgcn_s_setprio(0)

    f32x4 acc[8][4];
    const f32x4 zero = {0.f, 0.f, 0.f, 0.f};
#pragma unroll
    for (int m = 0; m < 8; ++m)
#pragma unroll
        for (int n = 0; n < 4; ++n) acc[m][n] = zero;

    bf16x8 faA[4][2], faB[4][2], fbA[2][2], fbB[2][2];

    const int nkt = Kc >> 6;   // K-tiles of 64 (even, >= 4)

    // prologue (FIFO order matters for the vmcnt analysis):
    // tile0 {Ah0,Bh0,Ah1,Bh1} + tile1 {Bh0,Ah0} = 12 loads
    STA(0, 0, 0); STB(0, 0, 0); STA(0, 1, 0); STB(0, 1, 0);
    STB(1, 0, 64); STA(1, 0, 64);
    VM6B;                       // tile0 Ah0,Bh0,Ah1 landed
    RD_A(0, 0, faA); RD_B(0, 0, fbA);

#pragma unroll 1
    for (int i = 0; i < (nkt - 2) / 2; ++i) {
        // ---- tile T = 2i (buf0) ----
        RD_A(0, 1, faB); STA(1, 1, 64);            // read Ah1(T); stage Ah1(T+1)
        MIDB; PRIO1; MFMA_Q(0, 0, faA, fbA); PRIO0; VM6B;
        RD_B(0, 1, fbB); STB(1, 1, 64);            // read Bh1(T); stage Bh1(T+1)
        MIDB; PRIO1; MFMA_Q(1, 0, faB, fbA); PRIO0; VM6B;
        RD_B(1, 0, fbA); STB(0, 0, 128);           // read Bh0(T+1); stage Bh0(T+2)
        MIDB; PRIO1; MFMA_Q(0, 1, faA, fbB); PRIO0; VM6B;
        RD_A(1, 0, faA); STA(0, 0, 128);           // read Ah0(T+1); stage Ah0(T+2)
        MIDB; PRIO1; MFMA_Q(1, 1, faB, fbB); PRIO0; VM6B;
        // ---- tile T+1 (buf1) ----
        RD_A(1, 1, faB); STA(0, 1, 128);           // read Ah1(T+1); stage Ah1(T+2)
        MIDB; PRIO1; MFMA_Q(0, 0, faA, fbA); PRIO0; VM6B;
        RD_B(1, 1, fbB); STB(0, 1, 128);           // read Bh1(T+1); stage Bh1(T+2)
        MIDB; PRIO1; MFMA_Q(1, 0, faB, fbA); PRIO0; VM6B;
        RD_B(0, 0, fbA); STB(1, 0, 192);           // read Bh0(T+2); stage Bh0(T+3)
        MIDB; PRIO1; MFMA_Q(0, 1, faA, fbB); PRIO0; VM6B;
        RD_A(0, 0, faA); STA(1, 0, 192);           // read Ah0(T+2); stage Ah0(T+3)
        MIDB; PRIO1; MFMA_Q(1, 1, faB, fbB); PRIO0; VM6B;
        gA += 128; gB += 128;                      // advance base by 2 tiles
    }
    {   // ---- epilogue: tile E = nkt-2 (buf0), tile F = nkt-1 (buf1) ----
        RD_A(0, 1, faB); STA(1, 1, 64);            // stage Ah1(F)
        MIDB; PRIO1; MFMA_Q(0, 0, faA, fbA); PRIO0; VM6B;
        RD_B(0, 1, fbB); STB(1, 1, 64);            // stage Bh1(F)
        MIDB; PRIO1; MFMA_Q(1, 0, faB, fbA); PRIO0; VM6B;
        RD_B(1, 0, fbA);                           // read Bh0(F)
        MIDB; PRIO1; MFMA_Q(0, 1, faA, fbB); PRIO0; VM4B;
        RD_A(1, 0, faA);                           // read Ah0(F)
        MIDB; PRIO1; MFMA_Q(1, 1, faB, fbB); PRIO0; VM2B;
        // tile F
        RD_A(1, 1, faB);                           // read Ah1(F)
        MIDB; PRIO1; MFMA_Q(0, 0, faA, fbA); PRIO0; VM0B;
        RD_B(1, 1, fbB);                           // read Bh1(F)
        PRIO1;
        MFMA_Q(1, 0, faB, fbA);
        MFMA_Q(0, 1, faA, fbB);
        MFMA_Q(1, 1, faB, fbB);
        PRIO0;
    }

    // C/D layout: col = lr (+16*ni within half), row = quad*4 + reg
#pragma unroll
    for (int m = 0; m < 8; ++m) {
        const int row0 = bm + (m >> 2) * 128 + wr * 64 + (m & 3) * 16 + quad * 4;
#pragma unroll
        for (int n = 0; n < 4; ++n) {
            const int col = bn + (n >> 1) * 128 + wc * 32 + (n & 1) * 16 + lr;
#pragma unroll
            for (int reg = 0; reg < 4; ++reg) {
                float v = acc[m][n][reg];
                if (OP == 0) {
                    float* Cf = (float*)Cout + (size_t)kz * czs;
                    Cf[(size_t)(row0 + reg) * ldc + col] = v;
                } else {  // OP == 2
                    if (col >= silu_col0) v = silu_f(v);
                    ((unsigned short*)Cout)[(size_t)(row0 + reg) * ldc + col] = f2b(v);
                }
            }
        }
    }
#undef STA
#undef STB
#undef LDA_F
#undef LDB_F
#undef RD_A
#undef RD_B
#undef MFMA_Q
#undef MIDB
#undef VM6B
#undef VM4B
#undef VM2B
#undef VM0B
#undef PRIO1
#undef PRIO0
}

// ---------- MFMA GEMM, 3-stage pipelined async LDS staging (128x128) ----------
// kept for x_proj (N=128) and dt_proj (K=96) which don't fit the 256^2 tiler.
// OP=0: fp32 store (+ split-K z, C offset kz*czs)
// OP=3: bf16 store of softplus(acc + bias[col])
template <int OP>
__global__ __launch_bounds__(256)
void gemm_mfma(const unsigned short* __restrict__ A, const unsigned short* __restrict__ W,
               void* __restrict__ Cout, int Kc, int lda, int ldw, int ldc,
               const float* __restrict__ bias, int silu_col0, long long czs) {
    __shared__ unsigned short As[3][4096];   // 3 x 128x32 bf16 = 24 KB
    __shared__ unsigned short Bs[3][4096];
    const int tid = threadIdx.x;
    const int bm = blockIdx.y * 128;
    const int bn = blockIdx.x * 128;
    const int kz = blockIdx.z;
    A += (size_t)kz * Kc;
    W += (size_t)kz * Kc;
    const int lane = tid & 63;
    const int wave = tid >> 6;
    const int r_a = lane >> 2;          // row within 16-row chunk
    const int k8 = (lane & 3) * 8;      // k offset (8 bf16 = 16B)

    const unsigned short* gA0 = A + (size_t)(bm + wave * 16 + r_a) * lda + k8;
    const unsigned short* gA1 = A + (size_t)(bm + 64 + wave * 16 + r_a) * lda + k8;
    const unsigned short* gB0 = W + (size_t)(bn + wave * 16 + r_a) * ldw + k8;
    const unsigned short* gB1 = W + (size_t)(bn + 64 + wave * 16 + r_a) * ldw + k8;

    const int wm = (wave & 1) * 64;
    const int wn = (wave >> 1) * 64;
    const int lr = lane & 15;
    const int quad = lane >> 4;

    f32x4 acc[4][4];
    const f32x4 zero = {0.f, 0.f, 0.f, 0.f};
#pragma unroll
    for (int i = 0; i < 4; i++)
#pragma unroll
        for (int j = 0; j < 4; j++) acc[i][j] = zero;

#define STAGE(koff, j) do { \
        gload16(gA0 + (koff), As[j] + wave * 512); \
        gload16(gA1 + (koff), As[j] + (wave + 4) * 512); \
        gload16(gB0 + (koff), Bs[j] + wave * 512); \
        gload16(gB1 + (koff), Bs[j] + (wave + 4) * 512); \
    } while (0)

    const int niter = Kc >> 5;
    STAGE(0, 0);
    if (niter > 1) STAGE(32, 1);

    int ib = 0;   // LDS buffer holding tile k
    for (int k = 0; k < niter; k++) {
        if (k + 1 < niter)
            asm volatile("s_waitcnt vmcnt(4)\n\ts_barrier" ::: "memory");
        else
            asm volatile("s_waitcnt vmcnt(0)\n\ts_barrier" ::: "memory");
        if (k + 2 < niter) {
            int is_ = ib + 2; if (is_ >= 3) is_ -= 3;
            STAGE((k + 2) << 5, is_);
        }
        const unsigned short* as = As[ib];
        const unsigned short* bs = Bs[ib];
        bf16x8 fa[4], fb[4];
#pragma unroll
        for (int mi = 0; mi < 4; mi++)
            fa[mi] = *reinterpret_cast<const bf16x8*>(as + (wm + mi * 16 + lr) * 32 + quad * 8);
#pragma unroll
        for (int ni = 0; ni < 4; ni++)
            fb[ni] = *reinterpret_cast<const bf16x8*>(bs + (wn + ni * 16 + lr) * 32 + quad * 8);
#pragma unroll
        for (int mi = 0; mi < 4; mi++)
#pragma unroll
            for (int ni = 0; ni < 4; ni++)
                acc[mi][ni] = __builtin_amdgcn_mfma_f32_16x16x32_bf16(fa[mi], fb[ni], acc[mi][ni], 0, 0, 0);
        ib = (ib == 2) ? 0 : ib + 1;
    }
#undef STAGE

    // C/D layout: col = lane&15 (+16*ni), row = quad*4 + reg (+16*mi)
#pragma unroll
    for (int mi = 0; mi < 4; mi++)
#pragma unroll
        for (int reg = 0; reg < 4; reg++) {
            int row = bm + wm + mi * 16 + quad * 4 + reg;
#pragma unroll
            for (int ni = 0; ni < 4; ni++) {
                int col = bn + wn + ni * 16 + lr;
                float v = acc[mi][ni][reg];
                if (OP == 0) {
                    float* Cf = (float*)Cout + (size_t)kz * czs;
                    Cf[(size_t)row * ldc + col] = v;
                } else if (OP == 2) {
                    if (col >= silu_col0) v = silu_f(v);
                    ((unsigned short*)Cout)[(size_t)row * ldc + col] = f2b(v);
                } else {  // OP == 3
                    ((unsigned short*)Cout)[(size_t)row * ldc + col] = f2b(softplus_f(v + bias[col]));
                }
            }
        }
}

// ---------- sum of 2 split-K partials -> out (float4) ----------
__global__ __launch_bounds__(256)
void reduce_out(const float* __restrict__ p, float* __restrict__ out, int n4) {
    int i = blockIdx.x * 256 + threadIdx.x;
    if (i >= n4) return;
    float4 a = reinterpret_cast<const float4*>(p)[i];
    float4 b = reinterpret_cast<const float4*>(p + (size_t)n4 * 4)[i];
    float4 o = {a.x + b.x, a.y + b.y, a.z + b.z, a.w + b.w};
    reinterpret_cast<float4*>(out)[i] = o;
}

// ---------- split-K reduction for x_proj; fuses dtin bf16 extraction ----------
__global__ __launch_bounds__(256)
void reduce_xpart(const float* __restrict__ xpart, float* __restrict__ ssmp,
                  unsigned short* __restrict__ dtin) {
    const int BL = 4096;
    int idx = blockIdx.x * 256 + threadIdx.x;   // BL*32 threads
    int row = idx >> 5;
    int c4 = (idx & 31) * 4;
    float4 s = {0.f, 0.f, 0.f, 0.f};
#pragma unroll
    for (int z = 0; z < 8; z++) {
        float4 v = *reinterpret_cast<const float4*>(xpart + (size_t)z * BL * 128 + (size_t)row * 128 + c4);
        s.x += v.x; s.y += v.y; s.z += v.z; s.w += v.w;
    }
    *reinterpret_cast<float4*>(ssmp + (size_t)row * 128 + c4) = s;
    if (c4 < 96) {
        ushort4 o;
        o.x = f2b(s.x); o.y = f2b(s.y); o.z = f2b(s.z); o.w = f2b(s.w);
        *reinterpret_cast<ushort4*>(dtin + (size_t)row * 96 + c4) = o;
    }
}

// ---------- causal depthwise conv (K=4) + SiLU, 8 channels/thread ----------
__global__ __launch_bounds__(256)
void conv_silu8(const unsigned short* __restrict__ projbf, const float* __restrict__ cw,
                const float* __restrict__ cb, unsigned short* __restrict__ xc) {
    const int I = 3072, L = 2048, LD = 6144;
    int idx = blockIdx.x * 256 + threadIdx.x;    // over BL*I/8
    int i8 = (idx % (I / 8)) * 8;
    int bl = idx / (I / 8);
    int l = bl & (L - 1);
    float s[8];
    {
        float4 b0 = *reinterpret_cast<const float4*>(cb + i8);
        float4 b1 = *reinterpret_cast<const float4*>(cb + i8 + 4);
        s[0]=b0.x; s[1]=b0.y; s[2]=b0.z; s[3]=b0.w; s[4]=b1.x; s[5]=b1.y; s[6]=b1.z; s[7]=b1.w;
    }
    float w[8][4];
#pragma unroll
    for (int c = 0; c < 8; c++) {
        float4 wr = *reinterpret_cast<const float4*>(cw + (i8 + c) * 4);
        w[c][0]=wr.x; w[c][1]=wr.y; w[c][2]=wr.z; w[c][3]=wr.w;
    }
#pragma unroll
    for (int j = 0; j < 4; j++) {
        if (l + j - 3 >= 0) {
            uint4 r = *reinterpret_cast<const uint4*>(projbf + (size_t)(bl + j - 3) * LD + i8);
            float xv[8];
            xv[0]=b2f((unsigned short)(r.x & 0xffff)); xv[1]=b2f((unsigned short)(r.x >> 16));
            xv[2]=b2f((unsigned short)(r.y & 0xffff)); xv[3]=b2f((unsigned short)(r.y >> 16));
            xv[4]=b2f((unsigned short)(r.z & 0xffff)); xv[5]=b2f((unsigned short)(r.z >> 16));
            xv[6]=b2f((unsigned short)(r.w & 0xffff)); xv[7]=b2f((unsigned short)(r.w >> 16));
#pragma unroll
            for (int c = 0; c < 8; c++) s[c] = fmaf(xv[c], w[c][j], s[c]);
        }
    }
    unsigned short o[8];
#pragma unroll
    for (int c = 0; c < 8; c++) o[c] = f2b(silu_f(s[c]));
    uint4 packed;
    packed.x = (unsigned)o[0] | ((unsigned)o[1] << 16);
    packed.y = (unsigned)o[2] | ((unsigned)o[3] << 16);
    packed.z = (unsigned)o[4] | ((unsigned)o[5] << 16);
    packed.w = (unsigned)o[6] | ((unsigned)o[7] << 16);
    *reinterpret_cast<uint4*>(xc + (size_t)bl * I + i8) = packed;
}

// ---------- pass A: per-chunk local scan (init 0) -> S_local, sumDelta ----------
__global__ __launch_bounds__(256)
void scan_passA(const unsigned short* __restrict__ delta_bf, const unsigned short* __restrict__ xc,
                const float* __restrict__ ssmp, const float* __restrict__ Aw,
                float* __restrict__ S_local, float* __restrict__ sumDelta) {
    const int I = 3072, L = 2048;
    __shared__ float bc[TCH][32];
    int g = blockIdx.x * 256 + threadIdx.x;
    int i = g % I;
    int bcid = g / I;
    int c = bcid % CCH;
    int b = bcid / CCH;
    size_t rowbase = (size_t)b * L + (size_t)c * TCH;
    for (int e = threadIdx.x; e < TCH * 8; e += 256) {
        int t = e >> 3, q = e & 7;
        float4 v = *reinterpret_cast<const float4*>(ssmp + (rowbase + t) * 128 + 96 + q * 4);
        *reinterpret_cast<float4*>(&bc[t][q * 4]) = v;
    }
    __syncthreads();

    float Arow[16];
#pragma unroll
    for (int n = 0; n < 16; n++) Arow[n] = Aw[i * 16 + n];
    float st[16];
#pragma unroll
    for (int n = 0; n < 16; n++) st[n] = 0.f;
    float sumD = 0.f;

    size_t rowI = rowbase * I + i;
    for (int t = 0; t < TCH; t++) {
        float delta = b2f(delta_bf[rowI]);
        float du = delta * b2f(xc[rowI]);
        sumD += delta;
        float4 b0 = *reinterpret_cast<const float4*>(&bc[t][0]);
        float4 b1 = *reinterpret_cast<const float4*>(&bc[t][4]);
        float4 b2 = *reinterpret_cast<const float4*>(&bc[t][8]);
        float4 b3 = *reinterpret_cast<const float4*>(&bc[t][12]);
        const float bv[16] = {b0.x,b0.y,b0.z,b0.w, b1.x,b1.y,b1.z,b1.w,
                              b2.x,b2.y,b2.z,b2.w, b3.x,b3.y,b3.z,b3.w};
#pragma unroll
        for (int n = 0; n < 16; n++)
            st[n] = fmaf(st[n], __expf(delta * Arow[n]), du * bv[n]);
        rowI += I;
    }
    size_t obase = (size_t)bcid * 16 * I + i;
#pragma unroll
    for (int n = 0; n < 16; n++) S_local[obase + (size_t)n * I] = st[n];
    sumDelta[(size_t)bcid * I + i] = sumD;
}

// ---------- pass B: sequential combine across chunks -> state_in ----------
__global__ __launch_bounds__(256)
void scan_passB(const float* __restrict__ S_local, const float* __restrict__ sumDelta,
                const float* __restrict__ Aw, float* __restrict__ state_in) {
    const int I = 3072;
    int g = blockIdx.x * 256 + threadIdx.x;
    int i = g % I;
    int bn = g / I;
    int n = bn & 15;
    int b = bn >> 4;
    float a = Aw[i * 16 + n];
    float state = 0.f;
    for (int c = 0; c < CCH; c++) {
        int bcid = b * CCH + c;
        size_t idx = ((size_t)bcid * 16 + n) * I + i;
        state_in[idx] = state;
        state = fmaf(state, __expf(a * sumDelta[(size_t)bcid * I + i]), S_local[idx]);
    }
}

// ---------- pass C: re-scan from state_in; fused y, D-skip, pre-silu'd gate ----------
__global__ __launch_bounds__(256)
void scan_passC(const unsigned short* __restrict__ projbf,   // silu(gate) at col 3072+i, ld 6144
                const unsigned short* __restrict__ xc,
                const float* __restrict__ ssmp, const unsigned short* __restrict__ delta_bf,
                const float* __restrict__ Aw, const float* __restrict__ Dw,
                const float* __restrict__ state_in, unsigned short* __restrict__ ybf) {
    const int I = 3072, L = 2048, LD = 6144;
    __shared__ float bc[TCH][32];
    int g = blockIdx.x * 256 + threadIdx.x;
    int i = g % I;
    int bcid = g / I;
    int c = bcid % CCH;
    int b = bcid / CCH;
    size_t rowbase = (size_t)b * L + (size_t)c * TCH;
    for (int e = threadIdx.x; e < TCH * 8; e += 256) {
        int t = e >> 3, q = e & 7;
        float4 v = *reinterpret_cast<const float4*>(ssmp + (rowbase + t) * 128 + 96 + q * 4);
        *reinterpret_cast<float4*>(&bc[t][q * 4]) = v;
    }
    __syncthreads();

    float Arow[16];
#pragma unroll
    for (int n = 0; n < 16; n++) Arow[n] = Aw[i * 16 + n];
    float Dv = Dw[i];
    float st[16];
    size_t sbase = (size_t)bcid * 16 * I + i;
#pragma unroll
    for (int n = 0; n < 16; n++) st[n] = state_in[sbase + (size_t)n * I];

    size_t rowI = rowbase * I + i;
    size_t rowG = rowbase * LD + I + i;
    for (int t = 0; t < TCH; t++) {
        float delta = b2f(delta_bf[rowI]);
        float u = b2f(xc[rowI]);
        float du = delta * u;
        float4 b0 = *reinterpret_cast<const float4*>(&bc[t][0]);
        float4 b1 = *reinterpret_cast<const float4*>(&bc[t][4]);
        float4 b2 = *reinterpret_cast<const float4*>(&bc[t][8]);
        float4 b3 = *reinterpret_cast<const float4*>(&bc[t][12]);
        float4 c0 = *reinterpret_cast<const float4*>(&bc[t][16]);
        float4 c1 = *reinterpret_cast<const float4*>(&bc[t][20]);
        float4 c2 = *reinterpret_cast<const float4*>(&bc[t][24]);
        float4 c3 = *reinterpret_cast<const float4*>(&bc[t][28]);
        const float bv[16] = {b0.x,b0.y,b0.z,b0.w, b1.x,b1.y,b1.z,b1.w,
                              b2.x,b2.y,b2.z,b2.w, b3.x,b3.y,b3.z,b3.w};
        const float cv[16] = {c0.x,c0.y,c0.z,c0.w, c1.x,c1.y,c1.z,c1.w,
                              c2.x,c2.y,c2.z,c2.w, c3.x,c3.y,c3.z,c3.w};
        float y = 0.f;
#pragma unroll
        for (int n = 0; n < 16; n++) {
            st[n] = fmaf(st[n], __expf(delta * Arow[n]), du * bv[n]);
            y = fmaf(st[n], cv[n], y);
        }
        y = fmaf(u, Dv, y);
        y *= b2f(projbf[rowG]);            // gate already silu'd in GEMM epilogue
        ybf[rowI] = f2b(y);
        rowI += I;
        rowG += LD;
    }
}

extern "C" void kernel_launch(void* const* d_in, const int* in_sizes, int n_in,
                              void* d_out, int out_size, void* d_ws, size_t ws_size,
                              hipStream_t stream) {
    const float* hidden  = (const float*)d_in[0];
    const float* W_in    = (const float*)d_in[1];
    const float* conv_w  = (const float*)d_in[2];
    const float* conv_b  = (const float*)d_in[3];
    const float* W_x     = (const float*)d_in[4];
    const float* W_dt    = (const float*)d_in[5];
    const float* dt_bias = (const float*)d_in[6];
    const float* Aw      = (const float*)d_in[7];
    const float* Dw      = (const float*)d_in[8];
    const float* W_out   = (const float*)d_in[9];
    float* out = (float*)d_out;

    constexpr int Bsz = 2, L = 2048, H = 1536, I = 3072, R = 96;
    constexpr int BL = Bsz * L;        // 4096
    constexpr int TwoI = 2 * I;        // 6144

    // ---- workspace layout ----
    char* base = (char*)d_ws;
    unsigned short* proj_bf  = (unsigned short*)base; base += (size_t)BL * TwoI * 2;   // 50.3 MB
    unsigned short* delta_bf = (unsigned short*)base; base += (size_t)BL * I * 2;      // 25.2 MB
    unsigned short* xc_bf    = (unsigned short*)base; base += (size_t)BL * I * 2;      // 25.2 MB
    unsigned short* y_bf     = (unsigned short*)base; base += (size_t)BL * I * 2;      // 25.2 MB
    float* ssmp              = (float*)base;          base += (size_t)BL * 128 * 4;    // 2.1 MB
    float* xpart             = (float*)base;          base += (size_t)8 * BL * 128 * 4;// 16.8 MB
    unsigned short* dtin_bf  = (unsigned short*)base; base += (size_t)BL * R * 2;      // 0.8 MB
    unsigned short* wx_bf    = (unsigned short*)base; base += (size_t)128 * I * 2;     // 0.8 MB
    unsigned short* wdt_bf   = (unsigned short*)base; base += (size_t)I * R * 2;       // 0.6 MB
    unsigned short* wout_bf  = (unsigned short*)base; base += (size_t)H * I * 2;       // 9.4 MB
    unsigned short* h_bf     = (unsigned short*)base; base += (size_t)BL * H * 2;      // 12.6 MB
    unsigned short* win_bf   = (unsigned short*)base; base += (size_t)TwoI * H * 2;    // 18.9 MB
    // scan scratch overlays h_bf+win_bf (dead after in_proj): 26.0 <= 31.5 MB
    float* S_local  = (float*)h_bf;
    float* sumDelta = S_local + (size_t)Bsz * CCH * 16 * I;
    float* state_in = sumDelta + (size_t)Bsz * CCH * I;
    // out_proj split-K partials overlay proj_bf (dead after passC):
    // 2 * 4096*1536*4 B = 50.3 MB == proj_bf size
    float* opart = (float*)proj_bf;

    dim3 blk(256);

    // 0) fused weight/act casts
    cast_all<<<(5283840 + 255) / 256, blk, 0, stream>>>(
        hidden, W_in, W_x, W_dt, W_out, h_bf, win_bf, wx_bf, wdt_bf, wout_bf);

    // 1) in_proj -> proj_bf [4096,6144] bf16; silu on gate half (cols >= 3072)
    //    grid 384 (%8==0), ntx=24 cols -> 3-col XCD stripes
    gemm256<2><<<dim3(24 * 16, 1, 1), dim3(512), 0, stream>>>(
        h_bf, win_bf, proj_bf, H, H, H, TwoI, /*ntx*/ TwoI / 256, /*nty*/ BL / 256,
        /*silu*/ I, 0);

    // 2) causal conv + SiLU -> xc_bf
    conv_silu8<<<BL * I / 8 / 256, blk, 0, stream>>>(proj_bf, conv_w, conv_b, xc_bf);

    // 3) x_proj split-K x8: xpart[z][4096][128] = xc @ wx^T (K chunk 384)
    gemm_mfma<0><<<dim3(1, BL / 128, 8), blk, 0, stream>>>(
        xc_bf, wx_bf, xpart, I / 8, I, I, 128, nullptr, 0, (long long)BL * 128);
    reduce_xpart<<<BL * 32 / 256, blk, 0, stream>>>(xpart, ssmp, dtin_bf);

    // 4) dt_proj, fused +bias & softplus -> delta_bf [4096,3072] bf16
    gemm_mfma<3><<<dim3(I / 128, BL / 128, 1), blk, 0, stream>>>(
        dtin_bf, wdt_bf, delta_bf, R, R, R, I, dt_bias, 0, 0);

    // 5) chunk-parallel selective scan
    scan_passA<<<Bsz * I * CCH / 256, blk, 0, stream>>>(
        delta_bf, xc_bf, ssmp, Aw, S_local, sumDelta);
    scan_passB<<<Bsz * 16 * I / 256, blk, 0, stream>>>(
        S_local, sumDelta, Aw, state_in);
    scan_passC<<<Bsz * I * CCH / 256, blk, 0, stream>>>(
        proj_bf, xc_bf, ssmp, delta_bf, Aw, Dw, state_in, y_bf);

    // 6) out_proj split-K x2 (96 blocks x2, %8==0), fp32 partials
    //    ntx=6 (not %8) -> 2-row XCD stripes (whole B resident in L2)
    gemm256<0><<<dim3(6 * 16, 1, 2), dim3(512), 0, stream>>>(
        y_bf, wout_bf, opart, I / 2, I, I, H, /*ntx*/ H / 256, /*nty*/ BL / 256,
        0, (long long)BL * H);
    reduce_out<<<BL * H / 4 / 256, blk, 0, stream>>>(opart, out, BL * H / 4);
}

// Round 4
// 479.681 us; speedup vs baseline: 1.3674x; 1.3674x over previous
//
#include <hip/hip_runtime.h>

typedef __attribute__((ext_vector_type(8))) short bf16x8;
typedef __attribute__((ext_vector_type(4))) float f32x4;

#define CCH 32   // chunks over L
#define TCH 64   // chunk length

// ---------- bf16 helpers (round-to-nearest-even) ----------
__device__ __forceinline__ unsigned short f2b(float f) {
    unsigned u = __float_as_uint(f);
    return (unsigned short)((u + 0x7fffu + ((u >> 16) & 1u)) >> 16);
}
__device__ __forceinline__ float b2f(unsigned short h) {
    return __uint_as_float(((unsigned)h) << 16);
}
__device__ __forceinline__ float softplus_f(float z) {
    return (z > 15.f) ? z : __logf(1.f + __expf(z));
}
__device__ __forceinline__ float silu_f(float g) {
    return g / (1.f + __expf(-g));
}

// async 16B/lane global->LDS (lds dst = wave-uniform base + lane*16)
__device__ __forceinline__ void gload16(const unsigned short* g, unsigned short* l) {
    __builtin_amdgcn_global_load_lds(
        (const __attribute__((address_space(1))) void*)g,
        (__attribute__((address_space(3))) void*)l, 16, 0, 0);
}

// ---------- fused fp32 -> bf16 cast for all 5 tensors ----------
__global__ __launch_bounds__(256)
void cast_all(const float* __restrict__ h, const float* __restrict__ win,
              const float* __restrict__ wx, const float* __restrict__ wdt,
              const float* __restrict__ wout,
              unsigned short* __restrict__ dh, unsigned short* __restrict__ dwin,
              unsigned short* __restrict__ dwx, unsigned short* __restrict__ dwdt,
              unsigned short* __restrict__ dwout) {
    const int n0 = 1572864, n1 = n0 + 2359296, n2 = n1 + 98304,
              n3 = n2 + 73728, n4 = n3 + 1179648;
    int i = blockIdx.x * 256 + threadIdx.x;
    const float* s; unsigned short* d; int off;
    if (i < n0)      { s = h;    d = dh;    off = i; }
    else if (i < n1) { s = win;  d = dwin;  off = i - n0; }
    else if (i < n2) { s = wx;   d = dwx;   off = i - n1; }
    else if (i < n3) { s = wdt;  d = dwdt;  off = i - n2; }
    else if (i < n4) { s = wout; d = dwout; off = i - n3; }
    else return;
    float4 v = reinterpret_cast<const float4*>(s)[off];
    ushort4 o;
    o.x = f2b(v.x); o.y = f2b(v.y); o.z = f2b(v.z); o.w = f2b(v.w);
    reinterpret_cast<ushort4*>(d)[off] = o;
}

// ============================================================================
// 256x256 GEMM, ONE barrier per K-tile, free-running tile body.
// C[M,N] = A[M,Kc] x W[N,Kc]^T, bf16, BK=64, 512 thr = 8 waves (2M x 4N).
// Per K-tile: stage tile t+1 into the OTHER double-buffer (8 global_load_lds,
// issued at tile top -> ~full-tile latency window), then 24 ds_read_b128 +
// 64 MFMA in gray-quadrant order (0,0)(0,1)(1,1)(1,0) with register reuse
// (fa0 spans Q00/Q01, fb1 spans Q01/Q11, fb0 revived for Q10).  NO intra-tile
// barriers and NO inline lgkmcnt: all LDS waits are compiler-derived counted
// waits from data deps, so the 2 waves/SIMD slip against each other and
// ds_read drain overlaps the MFMA issue stall.  Double buffers are FOUR
// DISTINCT __shared__ arrays + unroll-2 static naming so alias analysis
// proves gload-writes (next tile) disjoint from ds_reads (current tile).
// Single vmcnt(0)+s_barrier per tile: loads issued ~1700 cyc earlier (L2-hit
// ~200-300) so the drain is ~free (unlike short-BK m97 structure).
// Requires: Kc%128==0, M%256==0, N%256==0, grid.x%8==0.
// OP=0: fp32 store (+ split-K kz, C offset kz*czs); OP=2: bf16, silu for
// col >= silu_col0.
// ============================================================================
template <int OP>
__global__ __launch_bounds__(512)
void gemm256(const unsigned short* __restrict__ A, const unsigned short* __restrict__ W,
             void* __restrict__ Cout, int Kc, int lda, int ldw, int ldc,
             int ntx, int nty, int silu_col0, long long czs) {
    // 4 x 32 KB = 128 KB: [256 rows][64 cols] bf16 each, row stride 128 B
    __shared__ __align__(16) unsigned short A0s[16384];
    __shared__ __align__(16) unsigned short B0s[16384];
    __shared__ __align__(16) unsigned short A1s[16384];
    __shared__ __align__(16) unsigned short B1s[16384];
    const int tid  = threadIdx.x;
    const int lane = tid & 63;
    const int wave = tid >> 6;
    const int wr   = wave >> 2;    // 0..1 (M)
    const int wc   = wave & 3;     // 0..3 (N)
    const int lr   = lane & 15;
    const int quad = lane >> 4;
    const int sw   = lr & 7;       // read-side XOR

    // XCD-local stripe mapping (bijective; grid.x % 8 == 0)
    const int c = blockIdx.x & 7;
    const int j = blockIdx.x >> 3;
    int bm_t, bn_t;
    if ((ntx & 7) == 0) {          // column stripes per XCD
        const int cpx = ntx >> 3;
        bn_t = c * cpx + j % cpx;
        bm_t = j / cpx;
    } else {                       // row stripes per XCD (nty % 8 == 0)
        const int rpx = nty >> 3;
        bm_t = c * rpx + j % rpx;
        bn_t = j / rpx;
    }
    const int bm = bm_t * 256;
    const int bn = bn_t * 256;
    const int kz = blockIdx.z;
    A += (size_t)kz * Kc;
    W += (size_t)kz * Kc;

    // staging: each gload covers 64 rows (wave*8 + lane>>3 within), 16B slot
    // (lane&7); global col pre-swizzled by row&7 = (lane>>3)&7 (both-sides rule).
    const int rsub = wave * 8 + (lane >> 3);
    const int csw  = ((lane & 7) ^ ((lane >> 3) & 7)) * 8;
    const unsigned short* gA = A + (size_t)(bm + rsub) * lda + csw;
    const unsigned short* gB = W + (size_t)(bn + rsub) * ldw + csw;

    // stage full 256-row tile kt into ARR (4 gloads, 8 KB each)
#define STAGE_A(ARR, kt) do { \
        gload16(gA + (size_t)0   * lda + (kt) * 64, ARR + 0    + wave * 512); \
        gload16(gA + (size_t)64  * lda + (kt) * 64, ARR + 4096 + wave * 512); \
        gload16(gA + (size_t)128 * lda + (kt) * 64, ARR + 8192 + wave * 512); \
        gload16(gA + (size_t)192 * lda + (kt) * 64, ARR + 12288 + wave * 512); \
    } while (0)
#define STAGE_B(ARR, kt) do { \
        gload16(gB + (size_t)0   * ldw + (kt) * 64, ARR + 0    + wave * 512); \
        gload16(gB + (size_t)64  * ldw + (kt) * 64, ARR + 4096 + wave * 512); \
        gload16(gB + (size_t)128 * ldw + (kt) * 64, ARR + 8192 + wave * 512); \
        gload16(gB + (size_t)192 * ldw + (kt) * 64, ARR + 12288 + wave * 512); \
    } while (0)

    // swizzled fragment reads (slot = (kk*4+quad) ^ (row&7), row&7 == lr&7)
#define LDA_F(ARR, mh, mi, kk) \
    (*reinterpret_cast<const bf16x8*>(&ARR[((mh) * 128 + wr * 64 + (mi) * 16 + lr) * 64 + (((((kk) << 2) | quad)) ^ sw) * 8]))
#define LDB_F(ARR, nh, ni, kk) \
    (*reinterpret_cast<const bf16x8*>(&ARR[((nh) * 128 + wc * 32 + (ni) * 16 + lr) * 64 + (((((kk) << 2) | quad)) ^ sw) * 8]))

#define RD_A(ARR, mh, DST) do { \
        _Pragma("unroll") for (int mi = 0; mi < 4; ++mi) { \
            DST[mi][0] = LDA_F(ARR, mh, mi, 0); \
            DST[mi][1] = LDA_F(ARR, mh, mi, 1); } } while (0)
#define RD_B(ARR, nh, DST) do { \
        _Pragma("unroll") for (int ni = 0; ni < 2; ++ni) { \
            DST[ni][0] = LDB_F(ARR, nh, ni, 0); \
            DST[ni][1] = LDB_F(ARR, nh, ni, 1); } } while (0)

#define MFMA_Q(mh, nh, FA, FB) do { \
        _Pragma("unroll") for (int mi = 0; mi < 4; ++mi) \
        _Pragma("unroll") for (int ni = 0; ni < 2; ++ni) { \
            acc[(mh) * 4 + mi][(nh) * 2 + ni] = __builtin_amdgcn_mfma_f32_16x16x32_bf16(FA[mi][0], FB[ni][0], acc[(mh) * 4 + mi][(nh) * 2 + ni], 0, 0, 0); \
            acc[(mh) * 4 + mi][(nh) * 2 + ni] = __builtin_amdgcn_mfma_f32_16x16x32_bf16(FA[mi][1], FB[ni][1], acc[(mh) * 4 + mi][(nh) * 2 + ni], 0, 0, 0); } } while (0)

#define VM0B  asm volatile("s_waitcnt vmcnt(0)\n\ts_barrier" ::: "memory")
#define PRIO1 __builtin_amdgcn_s_setprio(1)
#define PRIO0 __builtin_amdgcn_s_setprio(0)

    // free-running tile body: gray-quadrant order, register reuse, no barriers
#define TILE_BODY(AX, BX) do { \
        RD_A(AX, 0, fa0); RD_B(BX, 0, fb0); \
        PRIO1; MFMA_Q(0, 0, fa0, fb0); PRIO0; \
        RD_B(BX, 1, fb1); \
        PRIO1; MFMA_Q(0, 1, fa0, fb1); PRIO0; \
        RD_A(AX, 1, fa1); \
        PRIO1; MFMA_Q(1, 1, fa1, fb1); PRIO0; \
        PRIO1; MFMA_Q(1, 0, fa1, fb0); PRIO0; \
    } while (0)

    f32x4 acc[8][4];
    const f32x4 zero = {0.f, 0.f, 0.f, 0.f};
#pragma unroll
    for (int m = 0; m < 8; ++m)
#pragma unroll
        for (int n = 0; n < 4; ++n) acc[m][n] = zero;

    bf16x8 fa0[4][2], fa1[4][2], fb0[2][2], fb1[2][2];

    const int nkt = Kc >> 6;   // K-tiles of 64 (even)

    // prologue: tile0 -> buf0
    STAGE_A(A0s, 0); STAGE_B(B0s, 0);
    VM0B;

#pragma unroll 1
    for (int t = 0; t < nkt; t += 2) {
        // tile t (buf0); stage t+1 -> buf1
        if (t + 1 < nkt) { STAGE_A(A1s, t + 1); STAGE_B(B1s, t + 1); }
        TILE_BODY(A0s, B0s);
        VM0B;
        // tile t+1 (buf1); stage t+2 -> buf0
        if (t + 1 < nkt) {
            if (t + 2 < nkt) { STAGE_A(A0s, t + 2); STAGE_B(B0s, t + 2); }
            TILE_BODY(A1s, B1s);
            VM0B;
        }
    }

    // C/D layout: col = lr (+16*ni within half), row = quad*4 + reg
#pragma unroll
    for (int m = 0; m < 8; ++m) {
        const int row0 = bm + (m >> 2) * 128 + wr * 64 + (m & 3) * 16 + quad * 4;
#pragma unroll
        for (int n = 0; n < 4; ++n) {
            const int col = bn + (n >> 1) * 128 + wc * 32 + (n & 1) * 16 + lr;
#pragma unroll
            for (int reg = 0; reg < 4; ++reg) {
                float v = acc[m][n][reg];
                if (OP == 0) {
                    float* Cf = (float*)Cout + (size_t)kz * czs;
                    Cf[(size_t)(row0 + reg) * ldc + col] = v;
                } else {  // OP == 2
                    if (col >= silu_col0) v = silu_f(v);
                    ((unsigned short*)Cout)[(size_t)(row0 + reg) * ldc + col] = f2b(v);
                }
            }
        }
    }
#undef STAGE_A
#undef STAGE_B
#undef LDA_F
#undef LDB_F
#undef RD_A
#undef RD_B
#undef MFMA_Q
#undef VM0B
#undef PRIO1
#undef PRIO0
#undef TILE_BODY
}

// ---------- MFMA GEMM, 3-stage pipelined async LDS staging (128x128) ----------
// kept for x_proj (N=128) and dt_proj (K=96) which don't fit the 256^2 tiler.
// OP=0: fp32 store (+ split-K z, C offset kz*czs)
// OP=3: bf16 store of softplus(acc + bias[col])
template <int OP>
__global__ __launch_bounds__(256)
void gemm_mfma(const unsigned short* __restrict__ A, const unsigned short* __restrict__ W,
               void* __restrict__ Cout, int Kc, int lda, int ldw, int ldc,
               const float* __restrict__ bias, int silu_col0, long long czs) {
    __shared__ unsigned short As[3][4096];   // 3 x 128x32 bf16 = 24 KB
    __shared__ unsigned short Bs[3][4096];
    const int tid = threadIdx.x;
    const int bm = blockIdx.y * 128;
    const int bn = blockIdx.x * 128;
    const int kz = blockIdx.z;
    A += (size_t)kz * Kc;
    W += (size_t)kz * Kc;
    const int lane = tid & 63;
    const int wave = tid >> 6;
    const int r_a = lane >> 2;          // row within 16-row chunk
    const int k8 = (lane & 3) * 8;      // k offset (8 bf16 = 16B)

    const unsigned short* gA0 = A + (size_t)(bm + wave * 16 + r_a) * lda + k8;
    const unsigned short* gA1 = A + (size_t)(bm + 64 + wave * 16 + r_a) * lda + k8;
    const unsigned short* gB0 = W + (size_t)(bn + wave * 16 + r_a) * ldw + k8;
    const unsigned short* gB1 = W + (size_t)(bn + 64 + wave * 16 + r_a) * ldw + k8;

    const int wm = (wave & 1) * 64;
    const int wn = (wave >> 1) * 64;
    const int lr = lane & 15;
    const int quad = lane >> 4;

    f32x4 acc[4][4];
    const f32x4 zero = {0.f, 0.f, 0.f, 0.f};
#pragma unroll
    for (int i = 0; i < 4; i++)
#pragma unroll
        for (int j = 0; j < 4; j++) acc[i][j] = zero;

#define STAGE(koff, j) do { \
        gload16(gA0 + (koff), As[j] + wave * 512); \
        gload16(gA1 + (koff), As[j] + (wave + 4) * 512); \
        gload16(gB0 + (koff), Bs[j] + wave * 512); \
        gload16(gB1 + (koff), Bs[j] + (wave + 4) * 512); \
    } while (0)

    const int niter = Kc >> 5;
    STAGE(0, 0);
    if (niter > 1) STAGE(32, 1);

    int ib = 0;   // LDS buffer holding tile k
    for (int k = 0; k < niter; k++) {
        if (k + 1 < niter)
            asm volatile("s_waitcnt vmcnt(4)\n\ts_barrier" ::: "memory");
        else
            asm volatile("s_waitcnt vmcnt(0)\n\ts_barrier" ::: "memory");
        if (k + 2 < niter) {
            int is_ = ib + 2; if (is_ >= 3) is_ -= 3;
            STAGE((k + 2) << 5, is_);
        }
        const unsigned short* as = As[ib];
        const unsigned short* bs = Bs[ib];
        bf16x8 fa[4], fb[4];
#pragma unroll
        for (int mi = 0; mi < 4; mi++)
            fa[mi] = *reinterpret_cast<const bf16x8*>(as + (wm + mi * 16 + lr) * 32 + quad * 8);
#pragma unroll
        for (int ni = 0; ni < 4; ni++)
            fb[ni] = *reinterpret_cast<const bf16x8*>(bs + (wn + ni * 16 + lr) * 32 + quad * 8);
#pragma unroll
        for (int mi = 0; mi < 4; mi++)
#pragma unroll
            for (int ni = 0; ni < 4; ni++)
                acc[mi][ni] = __builtin_amdgcn_mfma_f32_16x16x32_bf16(fa[mi], fb[ni], acc[mi][ni], 0, 0, 0);
        ib = (ib == 2) ? 0 : ib + 1;
    }
#undef STAGE

    // C/D layout: col = lane&15 (+16*ni), row = quad*4 + reg (+16*mi)
#pragma unroll
    for (int mi = 0; mi < 4; mi++)
#pragma unroll
        for (int reg = 0; reg < 4; reg++) {
            int row = bm + wm + mi * 16 + quad * 4 + reg;
#pragma unroll
            for (int ni = 0; ni < 4; ni++) {
                int col = bn + wn + ni * 16 + lr;
                float v = acc[mi][ni][reg];
                if (OP == 0) {
                    float* Cf = (float*)Cout + (size_t)kz * czs;
                    Cf[(size_t)row * ldc + col] = v;
                } else if (OP == 2) {
                    if (col >= silu_col0) v = silu_f(v);
                    ((unsigned short*)Cout)[(size_t)row * ldc + col] = f2b(v);
                } else {  // OP == 3
                    ((unsigned short*)Cout)[(size_t)row * ldc + col] = f2b(softplus_f(v + bias[col]));
                }
            }
        }
}

// ---------- sum of 2 split-K partials -> out (float4) ----------
__global__ __launch_bounds__(256)
void reduce_out(const float* __restrict__ p, float* __restrict__ out, int n4) {
    int i = blockIdx.x * 256 + threadIdx.x;
    if (i >= n4) return;
    float4 a = reinterpret_cast<const float4*>(p)[i];
    float4 b = reinterpret_cast<const float4*>(p + (size_t)n4 * 4)[i];
    float4 o = {a.x + b.x, a.y + b.y, a.z + b.z, a.w + b.w};
    reinterpret_cast<float4*>(out)[i] = o;
}

// ---------- split-K reduction for x_proj; fuses dtin bf16 extraction ----------
__global__ __launch_bounds__(256)
void reduce_xpart(const float* __restrict__ xpart, float* __restrict__ ssmp,
                  unsigned short* __restrict__ dtin) {
    const int BL = 4096;
    int idx = blockIdx.x * 256 + threadIdx.x;   // BL*32 threads
    int row = idx >> 5;
    int c4 = (idx & 31) * 4;
    float4 s = {0.f, 0.f, 0.f, 0.f};
#pragma unroll
    for (int z = 0; z < 8; z++) {
        float4 v = *reinterpret_cast<const float4*>(xpart + (size_t)z * BL * 128 + (size_t)row * 128 + c4);
        s.x += v.x; s.y += v.y; s.z += v.z; s.w += v.w;
    }
    *reinterpret_cast<float4*>(ssmp + (size_t)row * 128 + c4) = s;
    if (c4 < 96) {
        ushort4 o;
        o.x = f2b(s.x); o.y = f2b(s.y); o.z = f2b(s.z); o.w = f2b(s.w);
        *reinterpret_cast<ushort4*>(dtin + (size_t)row * 96 + c4) = o;
    }
}

// ---------- causal depthwise conv (K=4) + SiLU, 8 channels/thread ----------
__global__ __launch_bounds__(256)
void conv_silu8(const unsigned short* __restrict__ projbf, const float* __restrict__ cw,
                const float* __restrict__ cb, unsigned short* __restrict__ xc) {
    const int I = 3072, L = 2048, LD = 6144;
    int idx = blockIdx.x * 256 + threadIdx.x;    // over BL*I/8
    int i8 = (idx % (I / 8)) * 8;
    int bl = idx / (I / 8);
    int l = bl & (L - 1);
    float s[8];
    {
        float4 b0 = *reinterpret_cast<const float4*>(cb + i8);
        float4 b1 = *reinterpret_cast<const float4*>(cb + i8 + 4);
        s[0]=b0.x; s[1]=b0.y; s[2]=b0.z; s[3]=b0.w; s[4]=b1.x; s[5]=b1.y; s[6]=b1.z; s[7]=b1.w;
    }
    float w[8][4];
#pragma unroll
    for (int c = 0; c < 8; c++) {
        float4 wr = *reinterpret_cast<const float4*>(cw + (i8 + c) * 4);
        w[c][0]=wr.x; w[c][1]=wr.y; w[c][2]=wr.z; w[c][3]=wr.w;
    }
#pragma unroll
    for (int j = 0; j < 4; j++) {
        if (l + j - 3 >= 0) {
            uint4 r = *reinterpret_cast<const uint4*>(projbf + (size_t)(bl + j - 3) * LD + i8);
            float xv[8];
            xv[0]=b2f((unsigned short)(r.x & 0xffff)); xv[1]=b2f((unsigned short)(r.x >> 16));
            xv[2]=b2f((unsigned short)(r.y & 0xffff)); xv[3]=b2f((unsigned short)(r.y >> 16));
            xv[4]=b2f((unsigned short)(r.z & 0xffff)); xv[5]=b2f((unsigned short)(r.z >> 16));
            xv[6]=b2f((unsigned short)(r.w & 0xffff)); xv[7]=b2f((unsigned short)(r.w >> 16));
#pragma unroll
            for (int c = 0; c < 8; c++) s[c] = fmaf(xv[c], w[c][j], s[c]);
        }
    }
    unsigned short o[8];
#pragma unroll
    for (int c = 0; c < 8; c++) o[c] = f2b(silu_f(s[c]));
    uint4 packed;
    packed.x = (unsigned)o[0] | ((unsigned)o[1] << 16);
    packed.y = (unsigned)o[2] | ((unsigned)o[3] << 16);
    packed.z = (unsigned)o[4] | ((unsigned)o[5] << 16);
    packed.w = (unsigned)o[6] | ((unsigned)o[7] << 16);
    *reinterpret_cast<uint4*>(xc + (size_t)bl * I + i8) = packed;
}

// ---------- pass A: per-chunk local scan (init 0) -> S_local, sumDelta ----------
__global__ __launch_bounds__(256)
void scan_passA(const unsigned short* __restrict__ delta_bf, const unsigned short* __restrict__ xc,
                const float* __restrict__ ssmp, const float* __restrict__ Aw,
                float* __restrict__ S_local, float* __restrict__ sumDelta) {
    const int I = 3072, L = 2048;
    __shared__ float bc[TCH][32];
    int g = blockIdx.x * 256 + threadIdx.x;
    int i = g % I;
    int bcid = g / I;
    int c = bcid % CCH;
    int b = bcid / CCH;
    size_t rowbase = (size_t)b * L + (size_t)c * TCH;
    for (int e = threadIdx.x; e < TCH * 8; e += 256) {
        int t = e >> 3, q = e & 7;
        float4 v = *reinterpret_cast<const float4*>(ssmp + (rowbase + t) * 128 + 96 + q * 4);
        *reinterpret_cast<float4*>(&bc[t][q * 4]) = v;
    }
    __syncthreads();

    float Arow[16];
#pragma unroll
    for (int n = 0; n < 16; n++) Arow[n] = Aw[i * 16 + n];
    float st[16];
#pragma unroll
    for (int n = 0; n < 16; n++) st[n] = 0.f;
    float sumD = 0.f;

    size_t rowI = rowbase * I + i;
    for (int t = 0; t < TCH; t++) {
        float delta = b2f(delta_bf[rowI]);
        float du = delta * b2f(xc[rowI]);
        sumD += delta;
        float4 b0 = *reinterpret_cast<const float4*>(&bc[t][0]);
        float4 b1 = *reinterpret_cast<const float4*>(&bc[t][4]);
        float4 b2 = *reinterpret_cast<const float4*>(&bc[t][8]);
        float4 b3 = *reinterpret_cast<const float4*>(&bc[t][12]);
        const float bv[16] = {b0.x,b0.y,b0.z,b0.w, b1.x,b1.y,b1.z,b1.w,
                              b2.x,b2.y,b2.z,b2.w, b3.x,b3.y,b3.z,b3.w};
#pragma unroll
        for (int n = 0; n < 16; n++)
            st[n] = fmaf(st[n], __expf(delta * Arow[n]), du * bv[n]);
        rowI += I;
    }
    size_t obase = (size_t)bcid * 16 * I + i;
#pragma unroll
    for (int n = 0; n < 16; n++) S_local[obase + (size_t)n * I] = st[n];
    sumDelta[(size_t)bcid * I + i] = sumD;
}

// ---------- pass B: sequential combine across chunks -> state_in ----------
__global__ __launch_bounds__(256)
void scan_passB(const float* __restrict__ S_local, const float* __restrict__ sumDelta,
                const float* __restrict__ Aw, float* __restrict__ state_in) {
    const int I = 3072;
    int g = blockIdx.x * 256 + threadIdx.x;
    int i = g % I;
    int bn = g / I;
    int n = bn & 15;
    int b = bn >> 4;
    float a = Aw[i * 16 + n];
    float state = 0.f;
    for (int c = 0; c < CCH; c++) {
        int bcid = b * CCH + c;
        size_t idx = ((size_t)bcid * 16 + n) * I + i;
        state_in[idx] = state;
        state = fmaf(state, __expf(a * sumDelta[(size_t)bcid * I + i]), S_local[idx]);
    }
}

// ---------- pass C: re-scan from state_in; fused y, D-skip, pre-silu'd gate ----------
__global__ __launch_bounds__(256)
void scan_passC(const unsigned short* __restrict__ projbf,   // silu(gate) at col 3072+i, ld 6144
                const unsigned short* __restrict__ xc,
                const float* __restrict__ ssmp, const unsigned short* __restrict__ delta_bf,
                const float* __restrict__ Aw, const float* __restrict__ Dw,
                const float* __restrict__ state_in, unsigned short* __restrict__ ybf) {
    const int I = 3072, L = 2048, LD = 6144;
    __shared__ float bc[TCH][32];
    int g = blockIdx.x * 256 + threadIdx.x;
    int i = g % I;
    int bcid = g / I;
    int c = bcid % CCH;
    int b = bcid / CCH;
    size_t rowbase = (size_t)b * L + (size_t)c * TCH;
    for (int e = threadIdx.x; e < TCH * 8; e += 256) {
        int t = e >> 3, q = e & 7;
        float4 v = *reinterpret_cast<const float4*>(ssmp + (rowbase + t) * 128 + 96 + q * 4);
        *reinterpret_cast<float4*>(&bc[t][q * 4]) = v;
    }
    __syncthreads();

    float Arow[16];
#pragma unroll
    for (int n = 0; n < 16; n++) Arow[n] = Aw[i * 16 + n];
    float Dv = Dw[i];
    float st[16];
    size_t sbase = (size_t)bcid * 16 * I + i;
#pragma unroll
    for (int n = 0; n < 16; n++) st[n] = state_in[sbase + (size_t)n * I];

    size_t rowI = rowbase * I + i;
    size_t rowG = rowbase * LD + I + i;
    for (int t = 0; t < TCH; t++) {
        float delta = b2f(delta_bf[rowI]);
        float u = b2f(xc[rowI]);
        float du = delta * u;
        float4 b0 = *reinterpret_cast<const float4*>(&bc[t][0]);
        float4 b1 = *reinterpret_cast<const float4*>(&bc[t][4]);
        float4 b2 = *reinterpret_cast<const float4*>(&bc[t][8]);
        float4 b3 = *reinterpret_cast<const float4*>(&bc[t][12]);
        float4 c0 = *reinterpret_cast<const float4*>(&bc[t][16]);
        float4 c1 = *reinterpret_cast<const float4*>(&bc[t][20]);
        float4 c2 = *reinterpret_cast<const float4*>(&bc[t][24]);
        float4 c3 = *reinterpret_cast<const float4*>(&bc[t][28]);
        const float bv[16] = {b0.x,b0.y,b0.z,b0.w, b1.x,b1.y,b1.z,b1.w,
                              b2.x,b2.y,b2.z,b2.w, b3.x,b3.y,b3.z,b3.w};
        const float cv[16] = {c0.x,c0.y,c0.z,c0.w, c1.x,c1.y,c1.z,c1.w,
                              c2.x,c2.y,c2.z,c2.w, c3.x,c3.y,c3.z,c3.w};
        float y = 0.f;
#pragma unroll
        for (int n = 0; n < 16; n++) {
            st[n] = fmaf(st[n], __expf(delta * Arow[n]), du * bv[n]);
            y = fmaf(st[n], cv[n], y);
        }
        y = fmaf(u, Dv, y);
        y *= b2f(projbf[rowG]);            // gate already silu'd in GEMM epilogue
        ybf[rowI] = f2b(y);
        rowI += I;
        rowG += LD;
    }
}

extern "C" void kernel_launch(void* const* d_in, const int* in_sizes, int n_in,
                              void* d_out, int out_size, void* d_ws, size_t ws_size,
                              hipStream_t stream) {
    const float* hidden  = (const float*)d_in[0];
    const float* W_in    = (const float*)d_in[1];
    const float* conv_w  = (const float*)d_in[2];
    const float* conv_b  = (const float*)d_in[3];
    const float* W_x     = (const float*)d_in[4];
    const float* W_dt    = (const float*)d_in[5];
    const float* dt_bias = (const float*)d_in[6];
    const float* Aw      = (const float*)d_in[7];
    const float* Dw      = (const float*)d_in[8];
    const float* W_out   = (const float*)d_in[9];
    float* out = (float*)d_out;

    constexpr int Bsz = 2, L = 2048, H = 1536, I = 3072, R = 96;
    constexpr int BL = Bsz * L;        // 4096
    constexpr int TwoI = 2 * I;        // 6144

    // ---- workspace layout ----
    char* base = (char*)d_ws;
    unsigned short* proj_bf  = (unsigned short*)base; base += (size_t)BL * TwoI * 2;   // 50.3 MB
    unsigned short* delta_bf = (unsigned short*)base; base += (size_t)BL * I * 2;      // 25.2 MB
    unsigned short* xc_bf    = (unsigned short*)base; base += (size_t)BL * I * 2;      // 25.2 MB
    unsigned short* y_bf     = (unsigned short*)base; base += (size_t)BL * I * 2;      // 25.2 MB
    float* ssmp              = (float*)base;          base += (size_t)BL * 128 * 4;    // 2.1 MB
    float* xpart             = (float*)base;          base += (size_t)8 * BL * 128 * 4;// 16.8 MB
    unsigned short* dtin_bf  = (unsigned short*)base; base += (size_t)BL * R * 2;      // 0.8 MB
    unsigned short* wx_bf    = (unsigned short*)base; base += (size_t)128 * I * 2;     // 0.8 MB
    unsigned short* wdt_bf   = (unsigned short*)base; base += (size_t)I * R * 2;       // 0.6 MB
    unsigned short* wout_bf  = (unsigned short*)base; base += (size_t)H * I * 2;       // 9.4 MB
    unsigned short* h_bf     = (unsigned short*)base; base += (size_t)BL * H * 2;      // 12.6 MB
    unsigned short* win_bf   = (unsigned short*)base; base += (size_t)TwoI * H * 2;    // 18.9 MB
    // scan scratch overlays h_bf+win_bf (dead after in_proj): 26.0 <= 31.5 MB
    float* S_local  = (float*)h_bf;
    float* sumDelta = S_local + (size_t)Bsz * CCH * 16 * I;
    float* state_in = sumDelta + (size_t)Bsz * CCH * I;
    // out_proj split-K partials overlay proj_bf (dead after passC):
    // 2 * 4096*1536*4 B = 50.3 MB == proj_bf size
    float* opart = (float*)proj_bf;

    dim3 blk(256);

    // 0) fused weight/act casts
    cast_all<<<(5283840 + 255) / 256, blk, 0, stream>>>(
        hidden, W_in, W_x, W_dt, W_out, h_bf, win_bf, wx_bf, wdt_bf, wout_bf);

    // 1) in_proj -> proj_bf [4096,6144] bf16; silu on gate half (cols >= 3072)
    //    grid 384 (%8==0), ntx=24 cols -> 3-col XCD stripes
    gemm256<2><<<dim3(24 * 16, 1, 1), dim3(512), 0, stream>>>(
        h_bf, win_bf, proj_bf, H, H, H, TwoI, /*ntx*/ TwoI / 256, /*nty*/ BL / 256,
        /*silu*/ I, 0);

    // 2) causal conv + SiLU -> xc_bf
    conv_silu8<<<BL * I / 8 / 256, blk, 0, stream>>>(proj_bf, conv_w, conv_b, xc_bf);

    // 3) x_proj split-K x8: xpart[z][4096][128] = xc @ wx^T (K chunk 384)
    gemm_mfma<0><<<dim3(1, BL / 128, 8), blk, 0, stream>>>(
        xc_bf, wx_bf, xpart, I / 8, I, I, 128, nullptr, 0, (long long)BL * 128);
    reduce_xpart<<<BL * 32 / 256, blk, 0, stream>>>(xpart, ssmp, dtin_bf);

    // 4) dt_proj, fused +bias & softplus -> delta_bf [4096,3072] bf16
    gemm_mfma<3><<<dim3(I / 128, BL / 128, 1), blk, 0, stream>>>(
        dtin_bf, wdt_bf, delta_bf, R, R, R, I, dt_bias, 0, 0);

    // 5) chunk-parallel selective scan
    scan_passA<<<Bsz * I * CCH / 256, blk, 0, stream>>>(
        delta_bf, xc_bf, ssmp, Aw, S_local, sumDelta);
    scan_passB<<<Bsz * 16 * I / 256, blk, 0, stream>>>(
        S_local, sumDelta, Aw, state_in);
    scan_passC<<<Bsz * I * CCH / 256, blk, 0, stream>>>(
        proj_bf, xc_bf, ssmp, delta_bf, Aw, Dw, state_in, y_bf);

    // 6) out_proj split-K x2 (96 blocks x2, %8==0), fp32 partials
    //    ntx=6 (not %8) -> 2-row XCD stripes (whole B resident in L2)
    gemm256<0><<<dim3(6 * 16, 1, 2), dim3(512), 0, stream>>>(
        y_bf, wout_bf, opart, I / 2, I, I, H, /*ntx*/ H / 256, /*nty*/ BL / 256,
        0, (long long)BL * H);
    reduce_out<<<BL * H / 4 / 256, blk, 0, stream>>>(opart, out, BL * H / 4);
}

// Round 5
// 471.406 us; speedup vs baseline: 1.3914x; 1.0176x over previous
//
#include <hip/hip_runtime.h>

typedef __attribute__((ext_vector_type(8))) short bf16x8;
typedef __attribute__((ext_vector_type(4))) float f32x4;

#define CCH 32   // chunks over L
#define TCH 64   // chunk length

// ---------- bf16 helpers (round-to-nearest-even) ----------
__device__ __forceinline__ unsigned short f2b(float f) {
    unsigned u = __float_as_uint(f);
    return (unsigned short)((u + 0x7fffu + ((u >> 16) & 1u)) >> 16);
}
__device__ __forceinline__ float b2f(unsigned short h) {
    return __uint_as_float(((unsigned)h) << 16);
}
__device__ __forceinline__ float softplus_f(float z) {
    return (z > 15.f) ? z : __logf(1.f + __expf(z));
}
__device__ __forceinline__ float silu_f(float g) {
    return g / (1.f + __expf(-g));
}

// async 16B/lane global->LDS (lds dst = wave-uniform base + lane*16)
__device__ __forceinline__ void gload16(const unsigned short* g, unsigned short* l) {
    __builtin_amdgcn_global_load_lds(
        (const __attribute__((address_space(1))) void*)g,
        (__attribute__((address_space(3))) void*)l, 16, 0, 0);
}

// ---------- fused fp32 -> bf16 cast for all 5 tensors ----------
__global__ __launch_bounds__(256)
void cast_all(const float* __restrict__ h, const float* __restrict__ win,
              const float* __restrict__ wx, const float* __restrict__ wdt,
              const float* __restrict__ wout,
              unsigned short* __restrict__ dh, unsigned short* __restrict__ dwin,
              unsigned short* __restrict__ dwx, unsigned short* __restrict__ dwdt,
              unsigned short* __restrict__ dwout) {
    const int n0 = 1572864, n1 = n0 + 2359296, n2 = n1 + 98304,
              n3 = n2 + 73728, n4 = n3 + 1179648;
    int i = blockIdx.x * 256 + threadIdx.x;
    const float* s; unsigned short* d; int off;
    if (i < n0)      { s = h;    d = dh;    off = i; }
    else if (i < n1) { s = win;  d = dwin;  off = i - n0; }
    else if (i < n2) { s = wx;   d = dwx;   off = i - n1; }
    else if (i < n3) { s = wdt;  d = dwdt;  off = i - n2; }
    else if (i < n4) { s = wout; d = dwout; off = i - n3; }
    else return;
    float4 v = reinterpret_cast<const float4*>(s)[off];
    ushort4 o;
    o.x = f2b(v.x); o.y = f2b(v.y); o.z = f2b(v.z); o.w = f2b(v.w);
    reinterpret_cast<ushort4*>(d)[off] = o;
}

// ============================================================================
// 256x256 8-phase GEMM (r1 version, measured best for in_proj: 105 us).
// C[M,N] = A[M,Kc] x W[N,Kc]^T, bf16 in, BK=64, 512 thr = 8 waves (2M x 4N).
// OP=0: fp32 store (+ split-K kz, C offset kz*czs);  OP=2: bf16 store, silu
// applied for col >= silu_col0.
// ============================================================================
template <int OP>
__global__ __launch_bounds__(512)
void gemm256(const unsigned short* __restrict__ A, const unsigned short* __restrict__ W,
             void* __restrict__ Cout, int Kc, int lda, int ldw, int ldc,
             int ntx, int silu_col0, long long czs) {
    __shared__ __align__(16) unsigned short lds[65536];   // A[2][16384] | B[2][16384]
    const int tid  = threadIdx.x;
    const int lane = tid & 63;
    const int wave = tid >> 6;
    const int wr   = wave >> 2;    // 0..1 (M)
    const int wc   = wave & 3;     // 0..3 (N)
    const int lr   = lane & 15;
    const int quad = lane >> 4;
    const int sw   = lr & 7;       // read-side XOR

    // bijective XCD swizzle (gridDim.x % 8 == 0)
    const int nwg = gridDim.x;
    const int wg  = blockIdx.x;
    const int wgs = (wg & 7) * (nwg >> 3) + (wg >> 3);
    const int bm  = (wgs / ntx) * 256;
    const int bn  = (wgs % ntx) * 256;
    const int kz  = blockIdx.z;
    A += (size_t)kz * Kc;
    W += (size_t)kz * Kc;

    // staging: thread covers row (wave*8 + lane>>3) of each 64-row load op,
    // 16B slot (lane&7); global col pre-swizzled by row&7 = (lane>>3)&7.
    const int rsub = wave * 8 + (lane >> 3);
    const int csw  = ((lane & 7) ^ ((lane >> 3) & 7)) * 8;
    const unsigned short* gA = A + (size_t)(bm + rsub) * lda + csw;
    const unsigned short* gB = W + (size_t)(bn + rsub) * ldw + csw;

    // stage half h (128 rows) of tile kt into LDS buffer b (2 x gload16)
#define STA(b, h, kt) do { \
        gload16(gA + (size_t)((h) * 128) * lda + (kt) * 64,      &lds[(b) * 16384 + (h) * 8192 + wave * 512]); \
        gload16(gA + (size_t)((h) * 128 + 64) * lda + (kt) * 64, &lds[(b) * 16384 + (h) * 8192 + 4096 + wave * 512]); \
    } while (0)
#define STB(b, h, kt) do { \
        gload16(gB + (size_t)((h) * 128) * ldw + (kt) * 64,      &lds[32768 + (b) * 16384 + (h) * 8192 + wave * 512]); \
        gload16(gB + (size_t)((h) * 128 + 64) * ldw + (kt) * 64, &lds[32768 + (b) * 16384 + (h) * 8192 + 4096 + wave * 512]); \
    } while (0)

    // swizzled fragment reads (slot = (kk*4+quad) ^ (row&7), row&7 == lr&7)
#define LDA_F(b, mh, mi, kk) \
    (*reinterpret_cast<const bf16x8*>(&lds[(b) * 16384 + ((mh) * 128 + wr * 64 + (mi) * 16 + lr) * 64 + (((((kk) << 2) | quad)) ^ sw) * 8]))
#define LDB_F(b, nh, ni, kk) \
    (*reinterpret_cast<const bf16x8*>(&lds[32768 + (b) * 16384 + ((nh) * 128 + wc * 32 + (ni) * 16 + lr) * 64 + (((((kk) << 2) | quad)) ^ sw) * 8]))

#define RD_A(b, mh) do { \
        _Pragma("unroll") for (int mi = 0; mi < 4; ++mi) { \
            fa[mi][0] = LDA_F(b, mh, mi, 0); \
            fa[mi][1] = LDA_F(b, mh, mi, 1); } } while (0)
#define RD_B(b, nh, dst) do { \
        _Pragma("unroll") for (int ni = 0; ni < 2; ++ni) { \
            dst[ni][0] = LDB_F(b, nh, ni, 0); \
            dst[ni][1] = LDB_F(b, nh, ni, 1); } } while (0)

#define MFMA_Q(mh, nh, bb) do { \
        _Pragma("unroll") for (int mi = 0; mi < 4; ++mi) \
        _Pragma("unroll") for (int ni = 0; ni < 2; ++ni) { \
            acc[(mh) * 4 + mi][(nh) * 2 + ni] = __builtin_amdgcn_mfma_f32_16x16x32_bf16(fa[mi][0], bb[ni][0], acc[(mh) * 4 + mi][(nh) * 2 + ni], 0, 0, 0); \
            acc[(mh) * 4 + mi][(nh) * 2 + ni] = __builtin_amdgcn_mfma_f32_16x16x32_bf16(fa[mi][1], bb[ni][1], acc[(mh) * 4 + mi][(nh) * 2 + ni], 0, 0, 0); } } while (0)

#define MIDB  asm volatile("s_barrier" ::: "memory")
#define LGKM0 asm volatile("s_waitcnt lgkmcnt(0)" ::: "memory")
#define ENDB  asm volatile("s_barrier" ::: "memory")
#define ENDB_VM4 asm volatile("s_waitcnt vmcnt(4)\n\ts_barrier" ::: "memory")
#define ENDB_VM0 asm volatile("s_waitcnt vmcnt(0)\n\ts_barrier" ::: "memory")
#define PRIO1 __builtin_amdgcn_s_setprio(1)
#define PRIO0 __builtin_amdgcn_s_setprio(0)

    f32x4 acc[8][4];
    const f32x4 zero = {0.f, 0.f, 0.f, 0.f};
#pragma unroll
    for (int m = 0; m < 8; ++m)
#pragma unroll
        for (int n = 0; n < 4; ++n) acc[m][n] = zero;

    bf16x8 fa[4][2], fb0[2][2], fb1[2][2];

    const int nkt = Kc >> 6;   // K-tiles of 64 (even, >= 4)
    const int NT2 = nkt >> 1;

    // prologue: tile0 -> buf0 (all 4 halves), tile1 -> buf1 (A-h0, B-h0)
    STA(0, 0, 0); STB(0, 0, 0); STA(0, 1, 0); STB(0, 1, 0);
    STA(1, 0, 1); STB(1, 0, 1);
    ENDB_VM4;   // tile0 fully landed; tile1 h0 halves in flight

#pragma unroll 1
    for (int t = 0; t < NT2 - 1; ++t) {
        const int k1 = 2 * t + 1, k2 = 2 * t + 2, k3 = 2 * t + 3;
        // ph1: buf0 quad (0,0); stage buf1.Ah1 <- tile k1
        RD_A(0, 0); RD_B(0, 0, fb0); STA(1, 1, k1);
        MIDB; LGKM0; PRIO1; MFMA_Q(0, 0, fb0); PRIO0; ENDB;
        // ph2: buf0 (0,1); stage buf1.Bh1 <- k1
        RD_B(0, 1, fb1); STB(1, 1, k1);
        MIDB; LGKM0; PRIO1; MFMA_Q(0, 1, fb1); PRIO0; ENDB;
        // ph3: buf0 (1,0); stage buf0.Ah0 <- k2 (Ah0 last read ph1)
        RD_A(0, 1); STA(0, 0, k2);
        MIDB; LGKM0; PRIO1; MFMA_Q(1, 0, fb0); PRIO0; ENDB;
        // ph4: buf0 (1,1); stage buf0.Bh0 <- k2; vmcnt(4) retires tile k1
        STB(0, 0, k2);
        MIDB; PRIO1; MFMA_Q(1, 1, fb1); PRIO0; ENDB_VM4;
        // ph5: buf1 (0,0); stage buf0.Ah1 <- k2
        RD_A(1, 0); RD_B(1, 0, fb0); STA(0, 1, k2);
        MIDB; LGKM0; PRIO1; MFMA_Q(0, 0, fb0); PRIO0; ENDB;
        // ph6: buf1 (0,1); stage buf0.Bh1 <- k2
        RD_B(1, 1, fb1); STB(0, 1, k2);
        MIDB; LGKM0; PRIO1; MFMA_Q(0, 1, fb1); PRIO0; ENDB;
        // ph7: buf1 (1,0); stage buf1.Ah0 <- k3
        RD_A(1, 1); STA(1, 0, k3);
        MIDB; LGKM0; PRIO1; MFMA_Q(1, 0, fb0); PRIO0; ENDB;
        // ph8: buf1 (1,1); stage buf1.Bh0 <- k3; vmcnt(4) retires tile k2
        STB(1, 0, k3);
        MIDB; PRIO1; MFMA_Q(1, 1, fb1); PRIO0; ENDB_VM4;
    }
    {   // epilogue iter: tiles nkt-2 (buf0), nkt-1 (buf1); only ph1/ph2 stage
        const int k1 = nkt - 1;
        RD_A(0, 0); RD_B(0, 0, fb0); STA(1, 1, k1);
        MIDB; LGKM0; PRIO1; MFMA_Q(0, 0, fb0); PRIO0; ENDB;
        RD_B(0, 1, fb1); STB(1, 1, k1);
        MIDB; LGKM0; PRIO1; MFMA_Q(0, 1, fb1); PRIO0; ENDB;
        RD_A(0, 1);
        MIDB; LGKM0; PRIO1; MFMA_Q(1, 0, fb0); PRIO0; ENDB;
        MIDB; PRIO1; MFMA_Q(1, 1, fb1); PRIO0; ENDB_VM0;   // drain: tile nkt-1 landed
        RD_A(1, 0); RD_B(1, 0, fb0);
        MIDB; LGKM0; PRIO1; MFMA_Q(0, 0, fb0); PRIO0; ENDB;
        RD_B(1, 1, fb1);
        MIDB; LGKM0; PRIO1; MFMA_Q(0, 1, fb1); PRIO0; ENDB;
        RD_A(1, 1);
        MIDB; LGKM0; PRIO1; MFMA_Q(1, 0, fb0); PRIO0; ENDB;
        MIDB; PRIO1; MFMA_Q(1, 1, fb1); PRIO0;
    }

    // C/D layout: col = lr (+16*ni within half), row = quad*4 + reg
#pragma unroll
    for (int m = 0; m < 8; ++m) {
        const int row0 = bm + (m >> 2) * 128 + wr * 64 + (m & 3) * 16 + quad * 4;
#pragma unroll
        for (int n = 0; n < 4; ++n) {
            const int col = bn + (n >> 1) * 128 + wc * 32 + (n & 1) * 16 + lr;
#pragma unroll
            for (int reg = 0; reg < 4; ++reg) {
                float v = acc[m][n][reg];
                if (OP == 0) {
                    float* Cf = (float*)Cout + (size_t)kz * czs;
                    Cf[(size_t)(row0 + reg) * ldc + col] = v;
                } else {  // OP == 2
                    if (col >= silu_col0) v = silu_f(v);
                    ((unsigned short*)Cout)[(size_t)(row0 + reg) * ldc + col] = f2b(v);
                }
            }
        }
    }
#undef STA
#undef STB
#undef LDA_F
#undef LDB_F
#undef RD_A
#undef RD_B
#undef MFMA_Q
#undef MIDB
#undef LGKM0
#undef ENDB
#undef ENDB_VM4
#undef ENDB_VM0
#undef PRIO1
#undef PRIO0
}

// ============================================================================
// out_proj GEMM: 256M x 128N tile, free-running double-buffered body, fp32
// store DIRECT to d_out (no split-K partials, no reduce kernel).
// C[M,N] = A[M,Kc] x W[N,Kc]^T, bf16, BK=64, 512 thr = 8 waves (2M x 4N),
// per-wave C = 128x32.  Grid = 192 blocks (16 M-tiles x 12 N-tiles, one
// round on 256 CUs), K=3072 = 48 K-tiles.  LDS 96 KiB (A 2x32K, B 2x16K).
// XCD mapping: row stripes, rpx=2 (A-stripe 3 MB L2-resident per XCD).
// ============================================================================
__global__ __launch_bounds__(512)
void gemm_out(const unsigned short* __restrict__ A, const unsigned short* __restrict__ W,
              float* __restrict__ Cout, int Kc, int lda, int ldw, int ldc) {
    __shared__ __align__(16) unsigned short A0s[16384];
    __shared__ __align__(16) unsigned short B0s[8192];
    __shared__ __align__(16) unsigned short A1s[16384];
    __shared__ __align__(16) unsigned short B1s[8192];
    const int tid  = threadIdx.x;
    const int lane = tid & 63;
    const int wave = tid >> 6;
    const int wr   = wave >> 2;    // 0..1 (128-row half)
    const int wc   = wave & 3;     // 0..3 (32-col group)
    const int lr   = lane & 15;
    const int quad = lane >> 4;
    const int sw   = lr & 7;

    // XCD row-stripe mapping: 192 blocks, 16 M-tiles x 12 N-tiles, rpx=2
    const int c = blockIdx.x & 7;
    const int j = blockIdx.x >> 3;          // 0..23
    const int bm = (c * 2 + (j & 1)) * 256; // 0..15 -> rows
    const int bn = (j >> 1) * 128;          // 0..11 -> cols

    const int rsub = wave * 8 + (lane >> 3);
    const int csw  = ((lane & 7) ^ ((lane >> 3) & 7)) * 8;
    const unsigned short* gA = A + (size_t)(bm + rsub) * lda + csw;
    const unsigned short* gB = W + (size_t)(bn + rsub) * ldw + csw;

#define STAGE_A(ARR, kt) do { \
        gload16(gA + (size_t)0   * lda + (kt) * 64, ARR + 0     + wave * 512); \
        gload16(gA + (size_t)64  * lda + (kt) * 64, ARR + 4096  + wave * 512); \
        gload16(gA + (size_t)128 * lda + (kt) * 64, ARR + 8192  + wave * 512); \
        gload16(gA + (size_t)192 * lda + (kt) * 64, ARR + 12288 + wave * 512); \
    } while (0)
#define STAGE_B(ARR, kt) do { \
        gload16(gB + (size_t)0   * ldw + (kt) * 64, ARR + 0     + wave * 512); \
        gload16(gB + (size_t)64  * ldw + (kt) * 64, ARR + 4096  + wave * 512); \
    } while (0)

    // A rows: wr*128 + m*16 + lr (m 0..7); B rows: wc*32 + ni*16 + lr
#define LDA_F(ARR, m, kk) \
    (*reinterpret_cast<const bf16x8*>(&ARR[(wr * 128 + (m) * 16 + lr) * 64 + (((((kk) << 2) | quad)) ^ sw) * 8]))
#define LDB_F(ARR, ni, kk) \
    (*reinterpret_cast<const bf16x8*>(&ARR[(wc * 32 + (ni) * 16 + lr) * 64 + (((((kk) << 2) | quad)) ^ sw) * 8]))

#define PRIO1 __builtin_amdgcn_s_setprio(1)
#define PRIO0 __builtin_amdgcn_s_setprio(0)
#define VM0B  asm volatile("s_waitcnt vmcnt(0)\n\ts_barrier" ::: "memory")

#define TILE_BODY(AX, BX) do { \
        _Pragma("unroll") for (int ni = 0; ni < 2; ++ni) { \
            fb[ni][0] = LDB_F(BX, ni, 0); fb[ni][1] = LDB_F(BX, ni, 1); } \
        _Pragma("unroll") for (int m = 0; m < 4; ++m) { \
            fa0[m][0] = LDA_F(AX, m, 0); fa0[m][1] = LDA_F(AX, m, 1); } \
        PRIO1; \
        _Pragma("unroll") for (int m = 0; m < 4; ++m) \
        _Pragma("unroll") for (int ni = 0; ni < 2; ++ni) { \
            acc[m][ni] = __builtin_amdgcn_mfma_f32_16x16x32_bf16(fa0[m][0], fb[ni][0], acc[m][ni], 0, 0, 0); \
            acc[m][ni] = __builtin_amdgcn_mfma_f32_16x16x32_bf16(fa0[m][1], fb[ni][1], acc[m][ni], 0, 0, 0); } \
        PRIO0; \
        _Pragma("unroll") for (int m = 0; m < 4; ++m) { \
            fa1[m][0] = LDA_F(AX, m + 4, 0); fa1[m][1] = LDA_F(AX, m + 4, 1); } \
        PRIO1; \
        _Pragma("unroll") for (int m = 0; m < 4; ++m) \
        _Pragma("unroll") for (int ni = 0; ni < 2; ++ni) { \
            acc[m + 4][ni] = __builtin_amdgcn_mfma_f32_16x16x32_bf16(fa1[m][0], fb[ni][0], acc[m + 4][ni], 0, 0, 0); \
            acc[m + 4][ni] = __builtin_amdgcn_mfma_f32_16x16x32_bf16(fa1[m][1], fb[ni][1], acc[m + 4][ni], 0, 0, 0); } \
        PRIO0; \
    } while (0)

    f32x4 acc[8][2];
    const f32x4 zero = {0.f, 0.f, 0.f, 0.f};
#pragma unroll
    for (int m = 0; m < 8; ++m) { acc[m][0] = zero; acc[m][1] = zero; }

    bf16x8 fa0[4][2], fa1[4][2], fb[2][2];

    const int nkt = Kc >> 6;   // 48 (even)

    STAGE_A(A0s, 0); STAGE_B(B0s, 0);
    VM0B;

#pragma unroll 1
    for (int t = 0; t < nkt; t += 2) {
        if (t + 1 < nkt) { STAGE_A(A1s, t + 1); STAGE_B(B1s, t + 1); }
        TILE_BODY(A0s, B0s);
        VM0B;
        if (t + 1 < nkt) {
            if (t + 2 < nkt) { STAGE_A(A0s, t + 2); STAGE_B(B0s, t + 2); }
            TILE_BODY(A1s, B1s);
            VM0B;
        }
    }

    // C-write: row = bm + wr*128 + m*16 + quad*4 + reg; col = bn + wc*32 + ni*16 + lr
#pragma unroll
    for (int m = 0; m < 8; ++m) {
        const int row0 = bm + wr * 128 + m * 16 + quad * 4;
#pragma unroll
        for (int ni = 0; ni < 2; ++ni) {
            const int col = bn + wc * 32 + ni * 16 + lr;
#pragma unroll
            for (int reg = 0; reg < 4; ++reg)
                Cout[(size_t)(row0 + reg) * ldc + col] = acc[m][ni][reg];
        }
    }
#undef STAGE_A
#undef STAGE_B
#undef LDA_F
#undef LDB_F
#undef PRIO1
#undef PRIO0
#undef VM0B
#undef TILE_BODY
}

// ---------- MFMA GEMM, 3-stage pipelined async LDS staging (128x128) ----------
// kept for x_proj (N=128) and dt_proj (K=96) which don't fit the 256^2 tiler.
// OP=0: fp32 store (+ split-K z, C offset kz*czs)
// OP=3: bf16 store of softplus(acc + bias[col])
template <int OP>
__global__ __launch_bounds__(256)
void gemm_mfma(const unsigned short* __restrict__ A, const unsigned short* __restrict__ W,
               void* __restrict__ Cout, int Kc, int lda, int ldw, int ldc,
               const float* __restrict__ bias, int silu_col0, long long czs) {
    __shared__ unsigned short As[3][4096];   // 3 x 128x32 bf16 = 24 KB
    __shared__ unsigned short Bs[3][4096];
    const int tid = threadIdx.x;
    const int bm = blockIdx.y * 128;
    const int bn = blockIdx.x * 128;
    const int kz = blockIdx.z;
    A += (size_t)kz * Kc;
    W += (size_t)kz * Kc;
    const int lane = tid & 63;
    const int wave = tid >> 6;
    const int r_a = lane >> 2;          // row within 16-row chunk
    const int k8 = (lane & 3) * 8;      // k offset (8 bf16 = 16B)

    const unsigned short* gA0 = A + (size_t)(bm + wave * 16 + r_a) * lda + k8;
    const unsigned short* gA1 = A + (size_t)(bm + 64 + wave * 16 + r_a) * lda + k8;
    const unsigned short* gB0 = W + (size_t)(bn + wave * 16 + r_a) * ldw + k8;
    const unsigned short* gB1 = W + (size_t)(bn + 64 + wave * 16 + r_a) * ldw + k8;

    const int wm = (wave & 1) * 64;
    const int wn = (wave >> 1) * 64;
    const int lr = lane & 15;
    const int quad = lane >> 4;

    f32x4 acc[4][4];
    const f32x4 zero = {0.f, 0.f, 0.f, 0.f};
#pragma unroll
    for (int i = 0; i < 4; i++)
#pragma unroll
        for (int j = 0; j < 4; j++) acc[i][j] = zero;

#define STAGE(koff, j) do { \
        gload16(gA0 + (koff), As[j] + wave * 512); \
        gload16(gA1 + (koff), As[j] + (wave + 4) * 512); \
        gload16(gB0 + (koff), Bs[j] + wave * 512); \
        gload16(gB1 + (koff), Bs[j] + (wave + 4) * 512); \
    } while (0)

    const int niter = Kc >> 5;
    STAGE(0, 0);
    if (niter > 1) STAGE(32, 1);

    int ib = 0;   // LDS buffer holding tile k
    for (int k = 0; k < niter; k++) {
        if (k + 1 < niter)
            asm volatile("s_waitcnt vmcnt(4)\n\ts_barrier" ::: "memory");
        else
            asm volatile("s_waitcnt vmcnt(0)\n\ts_barrier" ::: "memory");
        if (k + 2 < niter) {
            int is_ = ib + 2; if (is_ >= 3) is_ -= 3;
            STAGE((k + 2) << 5, is_);
        }
        const unsigned short* as = As[ib];
        const unsigned short* bs = Bs[ib];
        bf16x8 fa[4], fb[4];
#pragma unroll
        for (int mi = 0; mi < 4; mi++)
            fa[mi] = *reinterpret_cast<const bf16x8*>(as + (wm + mi * 16 + lr) * 32 + quad * 8);
#pragma unroll
        for (int ni = 0; ni < 4; ni++)
            fb[ni] = *reinterpret_cast<const bf16x8*>(bs + (wn + ni * 16 + lr) * 32 + quad * 8);
#pragma unroll
        for (int mi = 0; mi < 4; mi++)
#pragma unroll
            for (int ni = 0; ni < 4; ni++)
                acc[mi][ni] = __builtin_amdgcn_mfma_f32_16x16x32_bf16(fa[mi], fb[ni], acc[mi][ni], 0, 0, 0);
        ib = (ib == 2) ? 0 : ib + 1;
    }
#undef STAGE

    // C/D layout: col = lane&15 (+16*ni), row = quad*4 + reg (+16*mi)
#pragma unroll
    for (int mi = 0; mi < 4; mi++)
#pragma unroll
        for (int reg = 0; reg < 4; reg++) {
            int row = bm + wm + mi * 16 + quad * 4 + reg;
#pragma unroll
            for (int ni = 0; ni < 4; ni++) {
                int col = bn + wn + ni * 16 + lr;
                float v = acc[mi][ni][reg];
                if (OP == 0) {
                    float* Cf = (float*)Cout + (size_t)kz * czs;
                    Cf[(size_t)row * ldc + col] = v;
                } else if (OP == 2) {
                    if (col >= silu_col0) v = silu_f(v);
                    ((unsigned short*)Cout)[(size_t)row * ldc + col] = f2b(v);
                } else {  // OP == 3
                    ((unsigned short*)Cout)[(size_t)row * ldc + col] = f2b(softplus_f(v + bias[col]));
                }
            }
        }
}

// ---------- split-K reduction for x_proj; fuses dtin bf16 extraction ----------
__global__ __launch_bounds__(256)
void reduce_xpart(const float* __restrict__ xpart, float* __restrict__ ssmp,
                  unsigned short* __restrict__ dtin) {
    const int BL = 4096;
    int idx = blockIdx.x * 256 + threadIdx.x;   // BL*32 threads
    int row = idx >> 5;
    int c4 = (idx & 31) * 4;
    float4 s = {0.f, 0.f, 0.f, 0.f};
#pragma unroll
    for (int z = 0; z < 8; z++) {
        float4 v = *reinterpret_cast<const float4*>(xpart + (size_t)z * BL * 128 + (size_t)row * 128 + c4);
        s.x += v.x; s.y += v.y; s.z += v.z; s.w += v.w;
    }
    *reinterpret_cast<float4*>(ssmp + (size_t)row * 128 + c4) = s;
    if (c4 < 96) {
        ushort4 o;
        o.x = f2b(s.x); o.y = f2b(s.y); o.z = f2b(s.z); o.w = f2b(s.w);
        *reinterpret_cast<ushort4*>(dtin + (size_t)row * 96 + c4) = o;
    }
}

// ---------- causal depthwise conv (K=4) + SiLU, 8 channels/thread ----------
__global__ __launch_bounds__(256)
void conv_silu8(const unsigned short* __restrict__ projbf, const float* __restrict__ cw,
                const float* __restrict__ cb, unsigned short* __restrict__ xc) {
    const int I = 3072, L = 2048, LD = 6144;
    int idx = blockIdx.x * 256 + threadIdx.x;    // over BL*I/8
    int i8 = (idx % (I / 8)) * 8;
    int bl = idx / (I / 8);
    int l = bl & (L - 1);
    float s[8];
    {
        float4 b0 = *reinterpret_cast<const float4*>(cb + i8);
        float4 b1 = *reinterpret_cast<const float4*>(cb + i8 + 4);
        s[0]=b0.x; s[1]=b0.y; s[2]=b0.z; s[3]=b0.w; s[4]=b1.x; s[5]=b1.y; s[6]=b1.z; s[7]=b1.w;
    }
    float w[8][4];
#pragma unroll
    for (int c = 0; c < 8; c++) {
        float4 wr = *reinterpret_cast<const float4*>(cw + (i8 + c) * 4);
        w[c][0]=wr.x; w[c][1]=wr.y; w[c][2]=wr.z; w[c][3]=wr.w;
    }
#pragma unroll
    for (int j = 0; j < 4; j++) {
        if (l + j - 3 >= 0) {
            uint4 r = *reinterpret_cast<const uint4*>(projbf + (size_t)(bl + j - 3) * LD + i8);
            float xv[8];
            xv[0]=b2f((unsigned short)(r.x & 0xffff)); xv[1]=b2f((unsigned short)(r.x >> 16));
            xv[2]=b2f((unsigned short)(r.y & 0xffff)); xv[3]=b2f((unsigned short)(r.y >> 16));
            xv[4]=b2f((unsigned short)(r.z & 0xffff)); xv[5]=b2f((unsigned short)(r.z >> 16));
            xv[6]=b2f((unsigned short)(r.w & 0xffff)); xv[7]=b2f((unsigned short)(r.w >> 16));
#pragma unroll
            for (int c = 0; c < 8; c++) s[c] = fmaf(xv[c], w[c][j], s[c]);
        }
    }
    unsigned short o[8];
#pragma unroll
    for (int c = 0; c < 8; c++) o[c] = f2b(silu_f(s[c]));
    uint4 packed;
    packed.x = (unsigned)o[0] | ((unsigned)o[1] << 16);
    packed.y = (unsigned)o[2] | ((unsigned)o[3] << 16);
    packed.z = (unsigned)o[4] | ((unsigned)o[5] << 16);
    packed.w = (unsigned)o[6] | ((unsigned)o[7] << 16);
    *reinterpret_cast<uint4*>(xc + (size_t)bl * I + i8) = packed;
}

// ---------- pass A: per-chunk local scan (init 0) -> S_local, sumDelta ----------
__global__ __launch_bounds__(256)
void scan_passA(const unsigned short* __restrict__ delta_bf, const unsigned short* __restrict__ xc,
                const float* __restrict__ ssmp, const float* __restrict__ Aw,
                float* __restrict__ S_local, float* __restrict__ sumDelta) {
    const int I = 3072, L = 2048;
    __shared__ float bc[TCH][32];
    int g = blockIdx.x * 256 + threadIdx.x;
    int i = g % I;
    int bcid = g / I;
    int c = bcid % CCH;
    int b = bcid / CCH;
    size_t rowbase = (size_t)b * L + (size_t)c * TCH;
    for (int e = threadIdx.x; e < TCH * 8; e += 256) {
        int t = e >> 3, q = e & 7;
        float4 v = *reinterpret_cast<const float4*>(ssmp + (rowbase + t) * 128 + 96 + q * 4);
        *reinterpret_cast<float4*>(&bc[t][q * 4]) = v;
    }
    __syncthreads();

    float Arow[16];
#pragma unroll
    for (int n = 0; n < 16; n++) Arow[n] = Aw[i * 16 + n];
    float st[16];
#pragma unroll
    for (int n = 0; n < 16; n++) st[n] = 0.f;
    float sumD = 0.f;

    size_t rowI = rowbase * I + i;
    for (int t = 0; t < TCH; t++) {
        float delta = b2f(delta_bf[rowI]);
        float du = delta * b2f(xc[rowI]);
        sumD += delta;
        float4 b0 = *reinterpret_cast<const float4*>(&bc[t][0]);
        float4 b1 = *reinterpret_cast<const float4*>(&bc[t][4]);
        float4 b2 = *reinterpret_cast<const float4*>(&bc[t][8]);
        float4 b3 = *reinterpret_cast<const float4*>(&bc[t][12]);
        const float bv[16] = {b0.x,b0.y,b0.z,b0.w, b1.x,b1.y,b1.z,b1.w,
                              b2.x,b2.y,b2.z,b2.w, b3.x,b3.y,b3.z,b3.w};
#pragma unroll
        for (int n = 0; n < 16; n++)
            st[n] = fmaf(st[n], __expf(delta * Arow[n]), du * bv[n]);
        rowI += I;
    }
    size_t obase = (size_t)bcid * 16 * I + i;
#pragma unroll
    for (int n = 0; n < 16; n++) S_local[obase + (size_t)n * I] = st[n];
    sumDelta[(size_t)bcid * I + i] = sumD;
}

// ---------- pass B: sequential combine across chunks -> state_in ----------
__global__ __launch_bounds__(256)
void scan_passB(const float* __restrict__ S_local, const float* __restrict__ sumDelta,
                const float* __restrict__ Aw, float* __restrict__ state_in) {
    const int I = 3072;
    int g = blockIdx.x * 256 + threadIdx.x;
    int i = g % I;
    int bn = g / I;
    int n = bn & 15;
    int b = bn >> 4;
    float a = Aw[i * 16 + n];
    float state = 0.f;
    for (int c = 0; c < CCH; c++) {
        int bcid = b * CCH + c;
        size_t idx = ((size_t)bcid * 16 + n) * I + i;
        state_in[idx] = state;
        state = fmaf(state, __expf(a * sumDelta[(size_t)bcid * I + i]), S_local[idx]);
    }
}

// ---------- pass C: re-scan from state_in; fused y, D-skip, pre-silu'd gate ----------
__global__ __launch_bounds__(256)
void scan_passC(const unsigned short* __restrict__ projbf,   // silu(gate) at col 3072+i, ld 6144
                const unsigned short* __restrict__ xc,
                const float* __restrict__ ssmp, const unsigned short* __restrict__ delta_bf,
                const float* __restrict__ Aw, const float* __restrict__ Dw,
                const float* __restrict__ state_in, unsigned short* __restrict__ ybf) {
    const int I = 3072, L = 2048, LD = 6144;
    __shared__ float bc[TCH][32];
    int g = blockIdx.x * 256 + threadIdx.x;
    int i = g % I;
    int bcid = g / I;
    int c = bcid % CCH;
    int b = bcid / CCH;
    size_t rowbase = (size_t)b * L + (size_t)c * TCH;
    for (int e = threadIdx.x; e < TCH * 8; e += 256) {
        int t = e >> 3, q = e & 7;
        float4 v = *reinterpret_cast<const float4*>(ssmp + (rowbase + t) * 128 + 96 + q * 4);
        *reinterpret_cast<float4*>(&bc[t][q * 4]) = v;
    }
    __syncthreads();

    float Arow[16];
#pragma unroll
    for (int n = 0; n < 16; n++) Arow[n] = Aw[i * 16 + n];
    float Dv = Dw[i];
    float st[16];
    size_t sbase = (size_t)bcid * 16 * I + i;
#pragma unroll
    for (int n = 0; n < 16; n++) st[n] = state_in[sbase + (size_t)n * I];

    size_t rowI = rowbase * I + i;
    size_t rowG = rowbase * LD + I + i;
    for (int t = 0; t < TCH; t++) {
        float delta = b2f(delta_bf[rowI]);
        float u = b2f(xc[rowI]);
        float du = delta * u;
        float4 b0 = *reinterpret_cast<const float4*>(&bc[t][0]);
        float4 b1 = *reinterpret_cast<const float4*>(&bc[t][4]);
        float4 b2 = *reinterpret_cast<const float4*>(&bc[t][8]);
        float4 b3 = *reinterpret_cast<const float4*>(&bc[t][12]);
        float4 c0 = *reinterpret_cast<const float4*>(&bc[t][16]);
        float4 c1 = *reinterpret_cast<const float4*>(&bc[t][20]);
        float4 c2 = *reinterpret_cast<const float4*>(&bc[t][24]);
        float4 c3 = *reinterpret_cast<const float4*>(&bc[t][28]);
        const float bv[16] = {b0.x,b0.y,b0.z,b0.w, b1.x,b1.y,b1.z,b1.w,
                              b2.x,b2.y,b2.z,b2.w, b3.x,b3.y,b3.z,b3.w};
        const float cv[16] = {c0.x,c0.y,c0.z,c0.w, c1.x,c1.y,c1.z,c1.w,
                              c2.x,c2.y,c2.z,c2.w, c3.x,c3.y,c3.z,c3.w};
        float y = 0.f;
#pragma unroll
        for (int n = 0; n < 16; n++) {
            st[n] = fmaf(st[n], __expf(delta * Arow[n]), du * bv[n]);
            y = fmaf(st[n], cv[n], y);
        }
        y = fmaf(u, Dv, y);
        y *= b2f(projbf[rowG]);            // gate already silu'd in GEMM epilogue
        ybf[rowI] = f2b(y);
        rowI += I;
        rowG += LD;
    }
}

extern "C" void kernel_launch(void* const* d_in, const int* in_sizes, int n_in,
                              void* d_out, int out_size, void* d_ws, size_t ws_size,
                              hipStream_t stream) {
    const float* hidden  = (const float*)d_in[0];
    const float* W_in    = (const float*)d_in[1];
    const float* conv_w  = (const float*)d_in[2];
    const float* conv_b  = (const float*)d_in[3];
    const float* W_x     = (const float*)d_in[4];
    const float* W_dt    = (const float*)d_in[5];
    const float* dt_bias = (const float*)d_in[6];
    const float* Aw      = (const float*)d_in[7];
    const float* Dw      = (const float*)d_in[8];
    const float* W_out   = (const float*)d_in[9];
    float* out = (float*)d_out;

    constexpr int Bsz = 2, L = 2048, H = 1536, I = 3072, R = 96;
    constexpr int BL = Bsz * L;        // 4096
    constexpr int TwoI = 2 * I;        // 6144

    // ---- workspace layout ----
    char* base = (char*)d_ws;
    unsigned short* proj_bf  = (unsigned short*)base; base += (size_t)BL * TwoI * 2;   // 50.3 MB
    unsigned short* delta_bf = (unsigned short*)base; base += (size_t)BL * I * 2;      // 25.2 MB
    unsigned short* xc_bf    = (unsigned short*)base; base += (size_t)BL * I * 2;      // 25.2 MB
    unsigned short* y_bf     = (unsigned short*)base; base += (size_t)BL * I * 2;      // 25.2 MB
    float* ssmp              = (float*)base;          base += (size_t)BL * 128 * 4;    // 2.1 MB
    float* xpart             = (float*)base;          base += (size_t)8 * BL * 128 * 4;// 16.8 MB
    unsigned short* dtin_bf  = (unsigned short*)base; base += (size_t)BL * R * 2;      // 0.8 MB
    unsigned short* wx_bf    = (unsigned short*)base; base += (size_t)128 * I * 2;     // 0.8 MB
    unsigned short* wdt_bf   = (unsigned short*)base; base += (size_t)I * R * 2;       // 0.6 MB
    unsigned short* wout_bf  = (unsigned short*)base; base += (size_t)H * I * 2;       // 9.4 MB
    unsigned short* h_bf     = (unsigned short*)base; base += (size_t)BL * H * 2;      // 12.6 MB
    unsigned short* win_bf   = (unsigned short*)base; base += (size_t)TwoI * H * 2;    // 18.9 MB
    // scan scratch overlays h_bf+win_bf (dead after in_proj): 26.0 <= 31.5 MB
    float* S_local  = (float*)h_bf;
    float* sumDelta = S_local + (size_t)Bsz * CCH * 16 * I;
    float* state_in = sumDelta + (size_t)Bsz * CCH * I;

    dim3 blk(256);

    // 0) fused weight/act casts
    cast_all<<<(5283840 + 255) / 256, blk, 0, stream>>>(
        hidden, W_in, W_x, W_dt, W_out, h_bf, win_bf, wx_bf, wdt_bf, wout_bf);

    // 1) in_proj -> proj_bf [4096,6144] bf16; silu on gate half (cols >= 3072)
    //    256^2 8-phase (r1, measured best): grid 384 (%8==0)
    gemm256<2><<<dim3(24 * 16, 1, 1), dim3(512), 0, stream>>>(
        h_bf, win_bf, proj_bf, H, H, H, TwoI, /*ntx*/ TwoI / 256, /*silu*/ I, 0);

    // 2) causal conv + SiLU -> xc_bf
    conv_silu8<<<BL * I / 8 / 256, blk, 0, stream>>>(proj_bf, conv_w, conv_b, xc_bf);

    // 3) x_proj split-K x8: xpart[z][4096][128] = xc @ wx^T (K chunk 384)
    gemm_mfma<0><<<dim3(1, BL / 128, 8), blk, 0, stream>>>(
        xc_bf, wx_bf, xpart, I / 8, I, I, 128, nullptr, 0, (long long)BL * 128);
    reduce_xpart<<<BL * 32 / 256, blk, 0, stream>>>(xpart, ssmp, dtin_bf);

    // 4) dt_proj, fused +bias & softplus -> delta_bf [4096,3072] bf16
    gemm_mfma<3><<<dim3(I / 128, BL / 128, 1), blk, 0, stream>>>(
        dtin_bf, wdt_bf, delta_bf, R, R, R, I, dt_bias, 0, 0);

    // 5) chunk-parallel selective scan
    scan_passA<<<Bsz * I * CCH / 256, blk, 0, stream>>>(
        delta_bf, xc_bf, ssmp, Aw, S_local, sumDelta);
    scan_passB<<<Bsz * 16 * I / 256, blk, 0, stream>>>(
        S_local, sumDelta, Aw, state_in);
    scan_passC<<<Bsz * I * CCH / 256, blk, 0, stream>>>(
        proj_bf, xc_bf, ssmp, delta_bf, Aw, Dw, state_in, y_bf);

    // 6) out_proj: single-pass 256x128 tiles, fp32 direct to out.
    //    grid 192 = 16 M-tiles x 12 N-tiles (one round), K=3072 (48 tiles)
    gemm_out<<<dim3(192, 1, 1), dim3(512), 0, stream>>>(
        y_bf, wout_bf, out, I, I, I, H);
}

// Round 6
// 461.800 us; speedup vs baseline: 1.4204x; 1.0208x over previous
//
#include <hip/hip_runtime.h>

typedef __attribute__((ext_vector_type(8))) short bf16x8;
typedef __attribute__((ext_vector_type(4))) float f32x4;

#define CCH 32   // chunks over L
#define TCH 64   // chunk length

// ---------- bf16 helpers (round-to-nearest-even) ----------
__device__ __forceinline__ unsigned short f2b(float f) {
    unsigned u = __float_as_uint(f);
    return (unsigned short)((u + 0x7fffu + ((u >> 16) & 1u)) >> 16);
}
__device__ __forceinline__ float b2f(unsigned short h) {
    return __uint_as_float(((unsigned)h) << 16);
}
__device__ __forceinline__ float softplus_f(float z) {
    return (z > 15.f) ? z : __logf(1.f + __expf(z));
}
__device__ __forceinline__ float silu_f(float g) {
    return g / (1.f + __expf(-g));
}

// async 16B/lane global->LDS (lds dst = wave-uniform base + lane*16)
__device__ __forceinline__ void gload16(const unsigned short* g, unsigned short* l) {
    __builtin_amdgcn_global_load_lds(
        (const __attribute__((address_space(1))) void*)g,
        (__attribute__((address_space(3))) void*)l, 16, 0, 0);
}

// ---------- fused fp32 -> bf16 cast for all 5 tensors ----------
__global__ __launch_bounds__(256)
void cast_all(const float* __restrict__ h, const float* __restrict__ win,
              const float* __restrict__ wx, const float* __restrict__ wdt,
              const float* __restrict__ wout,
              unsigned short* __restrict__ dh, unsigned short* __restrict__ dwin,
              unsigned short* __restrict__ dwx, unsigned short* __restrict__ dwdt,
              unsigned short* __restrict__ dwout) {
    const int n0 = 1572864, n1 = n0 + 2359296, n2 = n1 + 98304,
              n3 = n2 + 73728, n4 = n3 + 1179648;
    int i = blockIdx.x * 256 + threadIdx.x;
    const float* s; unsigned short* d; int off;
    if (i < n0)      { s = h;    d = dh;    off = i; }
    else if (i < n1) { s = win;  d = dwin;  off = i - n0; }
    else if (i < n2) { s = wx;   d = dwx;   off = i - n1; }
    else if (i < n3) { s = wdt;  d = dwdt;  off = i - n2; }
    else if (i < n4) { s = wout; d = dwout; off = i - n3; }
    else return;
    float4 v = reinterpret_cast<const float4*>(s)[off];
    ushort4 o;
    o.x = f2b(v.x); o.y = f2b(v.y); o.z = f2b(v.z); o.w = f2b(v.w);
    reinterpret_cast<ushort4*>(d)[off] = o;
}

// ============================================================================
// 256x256 8-phase GEMM (r1 version, measured best for in_proj: 105 us).
// C[M,N] = A[M,Kc] x W[N,Kc]^T, bf16 in, BK=64, 512 thr = 8 waves (2M x 4N).
// OP=0: fp32 store (+ split-K kz, C offset kz*czs);  OP=2: bf16 store, silu
// applied for col >= silu_col0.
// ============================================================================
template <int OP>
__global__ __launch_bounds__(512)
void gemm256(const unsigned short* __restrict__ A, const unsigned short* __restrict__ W,
             void* __restrict__ Cout, int Kc, int lda, int ldw, int ldc,
             int ntx, int silu_col0, long long czs) {
    __shared__ __align__(16) unsigned short lds[65536];   // A[2][16384] | B[2][16384]
    const int tid  = threadIdx.x;
    const int lane = tid & 63;
    const int wave = tid >> 6;
    const int wr   = wave >> 2;    // 0..1 (M)
    const int wc   = wave & 3;     // 0..3 (N)
    const int lr   = lane & 15;
    const int quad = lane >> 4;
    const int sw   = lr & 7;       // read-side XOR

    // bijective XCD swizzle (gridDim.x % 8 == 0)
    const int nwg = gridDim.x;
    const int wg  = blockIdx.x;
    const int wgs = (wg & 7) * (nwg >> 3) + (wg >> 3);
    const int bm  = (wgs / ntx) * 256;
    const int bn  = (wgs % ntx) * 256;
    const int kz  = blockIdx.z;
    A += (size_t)kz * Kc;
    W += (size_t)kz * Kc;

    // staging: thread covers row (wave*8 + lane>>3) of each 64-row load op,
    // 16B slot (lane&7); global col pre-swizzled by row&7 = (lane>>3)&7.
    const int rsub = wave * 8 + (lane >> 3);
    const int csw  = ((lane & 7) ^ ((lane >> 3) & 7)) * 8;
    const unsigned short* gA = A + (size_t)(bm + rsub) * lda + csw;
    const unsigned short* gB = W + (size_t)(bn + rsub) * ldw + csw;

    // stage half h (128 rows) of tile kt into LDS buffer b (2 x gload16)
#define STA(b, h, kt) do { \
        gload16(gA + (size_t)((h) * 128) * lda + (kt) * 64,      &lds[(b) * 16384 + (h) * 8192 + wave * 512]); \
        gload16(gA + (size_t)((h) * 128 + 64) * lda + (kt) * 64, &lds[(b) * 16384 + (h) * 8192 + 4096 + wave * 512]); \
    } while (0)
#define STB(b, h, kt) do { \
        gload16(gB + (size_t)((h) * 128) * ldw + (kt) * 64,      &lds[32768 + (b) * 16384 + (h) * 8192 + wave * 512]); \
        gload16(gB + (size_t)((h) * 128 + 64) * ldw + (kt) * 64, &lds[32768 + (b) * 16384 + (h) * 8192 + 4096 + wave * 512]); \
    } while (0)

    // swizzled fragment reads (slot = (kk*4+quad) ^ (row&7), row&7 == lr&7)
#define LDA_F(b, mh, mi, kk) \
    (*reinterpret_cast<const bf16x8*>(&lds[(b) * 16384 + ((mh) * 128 + wr * 64 + (mi) * 16 + lr) * 64 + (((((kk) << 2) | quad)) ^ sw) * 8]))
#define LDB_F(b, nh, ni, kk) \
    (*reinterpret_cast<const bf16x8*>(&lds[32768 + (b) * 16384 + ((nh) * 128 + wc * 32 + (ni) * 16 + lr) * 64 + (((((kk) << 2) | quad)) ^ sw) * 8]))

#define RD_A(b, mh) do { \
        _Pragma("unroll") for (int mi = 0; mi < 4; ++mi) { \
            fa[mi][0] = LDA_F(b, mh, mi, 0); \
            fa[mi][1] = LDA_F(b, mh, mi, 1); } } while (0)
#define RD_B(b, nh, dst) do { \
        _Pragma("unroll") for (int ni = 0; ni < 2; ++ni) { \
            dst[ni][0] = LDB_F(b, nh, ni, 0); \
            dst[ni][1] = LDB_F(b, nh, ni, 1); } } while (0)

#define MFMA_Q(mh, nh, bb) do { \
        _Pragma("unroll") for (int mi = 0; mi < 4; ++mi) \
        _Pragma("unroll") for (int ni = 0; ni < 2; ++ni) { \
            acc[(mh) * 4 + mi][(nh) * 2 + ni] = __builtin_amdgcn_mfma_f32_16x16x32_bf16(fa[mi][0], bb[ni][0], acc[(mh) * 4 + mi][(nh) * 2 + ni], 0, 0, 0); \
            acc[(mh) * 4 + mi][(nh) * 2 + ni] = __builtin_amdgcn_mfma_f32_16x16x32_bf16(fa[mi][1], bb[ni][1], acc[(mh) * 4 + mi][(nh) * 2 + ni], 0, 0, 0); } } while (0)

#define MIDB  asm volatile("s_barrier" ::: "memory")
#define LGKM0 asm volatile("s_waitcnt lgkmcnt(0)" ::: "memory")
#define ENDB  asm volatile("s_barrier" ::: "memory")
#define ENDB_VM4 asm volatile("s_waitcnt vmcnt(4)\n\ts_barrier" ::: "memory")
#define ENDB_VM0 asm volatile("s_waitcnt vmcnt(0)\n\ts_barrier" ::: "memory")
#define PRIO1 __builtin_amdgcn_s_setprio(1)
#define PRIO0 __builtin_amdgcn_s_setprio(0)

    f32x4 acc[8][4];
    const f32x4 zero = {0.f, 0.f, 0.f, 0.f};
#pragma unroll
    for (int m = 0; m < 8; ++m)
#pragma unroll
        for (int n = 0; n < 4; ++n) acc[m][n] = zero;

    bf16x8 fa[4][2], fb0[2][2], fb1[2][2];

    const int nkt = Kc >> 6;   // K-tiles of 64 (even, >= 4)
    const int NT2 = nkt >> 1;

    // prologue: tile0 -> buf0 (all 4 halves), tile1 -> buf1 (A-h0, B-h0)
    STA(0, 0, 0); STB(0, 0, 0); STA(0, 1, 0); STB(0, 1, 0);
    STA(1, 0, 1); STB(1, 0, 1);
    ENDB_VM4;   // tile0 fully landed; tile1 h0 halves in flight

#pragma unroll 1
    for (int t = 0; t < NT2 - 1; ++t) {
        const int k1 = 2 * t + 1, k2 = 2 * t + 2, k3 = 2 * t + 3;
        // ph1: buf0 quad (0,0); stage buf1.Ah1 <- tile k1
        RD_A(0, 0); RD_B(0, 0, fb0); STA(1, 1, k1);
        MIDB; LGKM0; PRIO1; MFMA_Q(0, 0, fb0); PRIO0; ENDB;
        // ph2: buf0 (0,1); stage buf1.Bh1 <- k1
        RD_B(0, 1, fb1); STB(1, 1, k1);
        MIDB; LGKM0; PRIO1; MFMA_Q(0, 1, fb1); PRIO0; ENDB;
        // ph3: buf0 (1,0); stage buf0.Ah0 <- k2 (Ah0 last read ph1)
        RD_A(0, 1); STA(0, 0, k2);
        MIDB; LGKM0; PRIO1; MFMA_Q(1, 0, fb0); PRIO0; ENDB;
        // ph4: buf0 (1,1); stage buf0.Bh0 <- k2; vmcnt(4) retires tile k1
        STB(0, 0, k2);
        MIDB; PRIO1; MFMA_Q(1, 1, fb1); PRIO0; ENDB_VM4;
        // ph5: buf1 (0,0); stage buf0.Ah1 <- k2
        RD_A(1, 0); RD_B(1, 0, fb0); STA(0, 1, k2);
        MIDB; LGKM0; PRIO1; MFMA_Q(0, 0, fb0); PRIO0; ENDB;
        // ph6: buf1 (0,1); stage buf0.Bh1 <- k2
        RD_B(1, 1, fb1); STB(0, 1, k2);
        MIDB; LGKM0; PRIO1; MFMA_Q(0, 1, fb1); PRIO0; ENDB;
        // ph7: buf1 (1,0); stage buf1.Ah0 <- k3
        RD_A(1, 1); STA(1, 0, k3);
        MIDB; LGKM0; PRIO1; MFMA_Q(1, 0, fb0); PRIO0; ENDB;
        // ph8: buf1 (1,1); stage buf1.Bh0 <- k3; vmcnt(4) retires tile k2
        STB(1, 0, k3);
        MIDB; PRIO1; MFMA_Q(1, 1, fb1); PRIO0; ENDB_VM4;
    }
    {   // epilogue iter: tiles nkt-2 (buf0), nkt-1 (buf1); only ph1/ph2 stage
        const int k1 = nkt - 1;
        RD_A(0, 0); RD_B(0, 0, fb0); STA(1, 1, k1);
        MIDB; LGKM0; PRIO1; MFMA_Q(0, 0, fb0); PRIO0; ENDB;
        RD_B(0, 1, fb1); STB(1, 1, k1);
        MIDB; LGKM0; PRIO1; MFMA_Q(0, 1, fb1); PRIO0; ENDB;
        RD_A(0, 1);
        MIDB; LGKM0; PRIO1; MFMA_Q(1, 0, fb0); PRIO0; ENDB;
        MIDB; PRIO1; MFMA_Q(1, 1, fb1); PRIO0; ENDB_VM0;   // drain: tile nkt-1 landed
        RD_A(1, 0); RD_B(1, 0, fb0);
        MIDB; LGKM0; PRIO1; MFMA_Q(0, 0, fb0); PRIO0; ENDB;
        RD_B(1, 1, fb1);
        MIDB; LGKM0; PRIO1; MFMA_Q(0, 1, fb1); PRIO0; ENDB;
        RD_A(1, 1);
        MIDB; LGKM0; PRIO1; MFMA_Q(1, 0, fb0); PRIO0; ENDB;
        MIDB; PRIO1; MFMA_Q(1, 1, fb1); PRIO0;
    }

    // C/D layout: col = lr (+16*ni within half), row = quad*4 + reg
#pragma unroll
    for (int m = 0; m < 8; ++m) {
        const int row0 = bm + (m >> 2) * 128 + wr * 64 + (m & 3) * 16 + quad * 4;
#pragma unroll
        for (int n = 0; n < 4; ++n) {
            const int col = bn + (n >> 1) * 128 + wc * 32 + (n & 1) * 16 + lr;
#pragma unroll
            for (int reg = 0; reg < 4; ++reg) {
                float v = acc[m][n][reg];
                if (OP == 0) {
                    float* Cf = (float*)Cout + (size_t)kz * czs;
                    Cf[(size_t)(row0 + reg) * ldc + col] = v;
                } else {  // OP == 2
                    if (col >= silu_col0) v = silu_f(v);
                    ((unsigned short*)Cout)[(size_t)(row0 + reg) * ldc + col] = f2b(v);
                }
            }
        }
    }
#undef STA
#undef STB
#undef LDA_F
#undef LDB_F
#undef RD_A
#undef RD_B
#undef MFMA_Q
#undef MIDB
#undef LGKM0
#undef ENDB
#undef ENDB_VM4
#undef ENDB_VM0
#undef PRIO1
#undef PRIO0
}

// ============================================================================
// out_proj GEMM: 128M x 192N tile, grid EXACTLY 256 blocks (one full round on
// 256 CUs), K=3072 single pass, fp32 direct to d_out.
// C[M,N] = A[M,Kc] x W[N,Kc]^T, bf16, BK=64, 512 thr = 8 waves (2M x 4N),
// per-wave C = 64x48 (4x3 frags, acc 48 VGPR).  LDS 80 KiB (A 2x16K, B 2x24K)
// double-buffered, free-running body with per-tile vmcnt(0).
// XCD mapping: XCD c owns one 192-col B-stripe (192x3072 bf16 = 1.18 MB,
// L2-resident); A panel streams through L3.
// ============================================================================
__global__ __launch_bounds__(512)
void gemm_out(const unsigned short* __restrict__ A, const unsigned short* __restrict__ W,
              float* __restrict__ Cout, int Kc, int lda, int ldw, int ldc) {
    __shared__ __align__(16) unsigned short A0s[8192];    // 128x64 bf16
    __shared__ __align__(16) unsigned short B0s[12288];   // 192x64 bf16
    __shared__ __align__(16) unsigned short A1s[8192];
    __shared__ __align__(16) unsigned short B1s[12288];
    const int tid  = threadIdx.x;
    const int lane = tid & 63;
    const int wave = tid >> 6;
    const int wr   = wave >> 2;    // 0..1 (64-row half)
    const int wc   = wave & 3;     // 0..3 (48-col group)
    const int lr   = lane & 15;
    const int quad = lane >> 4;
    const int sw   = lr & 7;

    // grid 256 = 8 XCD col-stripes x 32 M-tiles
    const int c  = blockIdx.x & 7;
    const int j  = blockIdx.x >> 3;   // 0..31
    const int bm = j * 128;
    const int bn = c * 192;

    const int rsub = wave * 8 + (lane >> 3);
    const int csw  = ((lane & 7) ^ ((lane >> 3) & 7)) * 8;
    const unsigned short* gA = A + (size_t)(bm + rsub) * lda + csw;
    const unsigned short* gB = W + (size_t)(bn + rsub) * ldw + csw;

    // each gload16 covers 64 rows x 64 cols (8 KB)
#define STAGE_A(ARR, kt) do { \
        gload16(gA + (size_t)0  * lda + (kt) * 64, ARR + 0    + wave * 512); \
        gload16(gA + (size_t)64 * lda + (kt) * 64, ARR + 4096 + wave * 512); \
    } while (0)
#define STAGE_B(ARR, kt) do { \
        gload16(gB + (size_t)0   * ldw + (kt) * 64, ARR + 0    + wave * 512); \
        gload16(gB + (size_t)64  * ldw + (kt) * 64, ARR + 4096 + wave * 512); \
        gload16(gB + (size_t)128 * ldw + (kt) * 64, ARR + 8192 + wave * 512); \
    } while (0)

    // A row = wr*64 + mi*16 + lr; B row = wc*48 + ni*16 + lr (row&7 == lr&7)
#define LDA_F(ARR, mi, kk) \
    (*reinterpret_cast<const bf16x8*>(&ARR[(wr * 64 + (mi) * 16 + lr) * 64 + (((((kk) << 2) | quad)) ^ sw) * 8]))
#define LDB_F(ARR, ni, kk) \
    (*reinterpret_cast<const bf16x8*>(&ARR[(wc * 48 + (ni) * 16 + lr) * 64 + (((((kk) << 2) | quad)) ^ sw) * 8]))

#define PRIO1 __builtin_amdgcn_s_setprio(1)
#define PRIO0 __builtin_amdgcn_s_setprio(0)
#define VM0B  asm volatile("s_waitcnt vmcnt(0)\n\ts_barrier" ::: "memory")

#define TILE_BODY(AX, BX) do { \
        _Pragma("unroll") for (int ni = 0; ni < 3; ++ni) { \
            fb[ni][0] = LDB_F(BX, ni, 0); fb[ni][1] = LDB_F(BX, ni, 1); } \
        _Pragma("unroll") for (int mi = 0; mi < 4; ++mi) { \
            fa[mi][0] = LDA_F(AX, mi, 0); fa[mi][1] = LDA_F(AX, mi, 1); } \
        PRIO1; \
        _Pragma("unroll") for (int mi = 0; mi < 4; ++mi) \
        _Pragma("unroll") for (int ni = 0; ni < 3; ++ni) { \
            acc[mi][ni] = __builtin_amdgcn_mfma_f32_16x16x32_bf16(fa[mi][0], fb[ni][0], acc[mi][ni], 0, 0, 0); \
            acc[mi][ni] = __builtin_amdgcn_mfma_f32_16x16x32_bf16(fa[mi][1], fb[ni][1], acc[mi][ni], 0, 0, 0); } \
        PRIO0; \
    } while (0)

    f32x4 acc[4][3];
    const f32x4 zero = {0.f, 0.f, 0.f, 0.f};
#pragma unroll
    for (int m = 0; m < 4; ++m)
#pragma unroll
        for (int n = 0; n < 3; ++n) acc[m][n] = zero;

    bf16x8 fa[4][2], fb[3][2];

    const int nkt = Kc >> 6;   // 48 (even)

    STAGE_A(A0s, 0); STAGE_B(B0s, 0);
    VM0B;

#pragma unroll 1
    for (int t = 0; t < nkt; t += 2) {
        if (t + 1 < nkt) { STAGE_A(A1s, t + 1); STAGE_B(B1s, t + 1); }
        TILE_BODY(A0s, B0s);
        VM0B;
        if (t + 1 < nkt) {
            if (t + 2 < nkt) { STAGE_A(A0s, t + 2); STAGE_B(B0s, t + 2); }
            TILE_BODY(A1s, B1s);
            VM0B;
        }
    }

    // C-write: row = bm + wr*64 + mi*16 + quad*4 + reg; col = bn + wc*48 + ni*16 + lr
#pragma unroll
    for (int mi = 0; mi < 4; ++mi) {
        const int row0 = bm + wr * 64 + mi * 16 + quad * 4;
#pragma unroll
        for (int ni = 0; ni < 3; ++ni) {
            const int col = bn + wc * 48 + ni * 16 + lr;
#pragma unroll
            for (int reg = 0; reg < 4; ++reg)
                Cout[(size_t)(row0 + reg) * ldc + col] = acc[mi][ni][reg];
        }
    }
#undef STAGE_A
#undef STAGE_B
#undef LDA_F
#undef LDB_F
#undef PRIO1
#undef PRIO0
#undef VM0B
#undef TILE_BODY
}

// ---------- MFMA GEMM, 3-stage pipelined async LDS staging (128x128) ----------
// kept for x_proj (N=128) and dt_proj (K=96) which don't fit the 256^2 tiler.
// OP=0: fp32 store (+ split-K z, C offset kz*czs)
// OP=3: bf16 store of softplus(acc + bias[col])
template <int OP>
__global__ __launch_bounds__(256)
void gemm_mfma(const unsigned short* __restrict__ A, const unsigned short* __restrict__ W,
               void* __restrict__ Cout, int Kc, int lda, int ldw, int ldc,
               const float* __restrict__ bias, int silu_col0, long long czs) {
    __shared__ unsigned short As[3][4096];   // 3 x 128x32 bf16 = 24 KB
    __shared__ unsigned short Bs[3][4096];
    const int tid = threadIdx.x;
    const int bm = blockIdx.y * 128;
    const int bn = blockIdx.x * 128;
    const int kz = blockIdx.z;
    A += (size_t)kz * Kc;
    W += (size_t)kz * Kc;
    const int lane = tid & 63;
    const int wave = tid >> 6;
    const int r_a = lane >> 2;          // row within 16-row chunk
    const int k8 = (lane & 3) * 8;      // k offset (8 bf16 = 16B)

    const unsigned short* gA0 = A + (size_t)(bm + wave * 16 + r_a) * lda + k8;
    const unsigned short* gA1 = A + (size_t)(bm + 64 + wave * 16 + r_a) * lda + k8;
    const unsigned short* gB0 = W + (size_t)(bn + wave * 16 + r_a) * ldw + k8;
    const unsigned short* gB1 = W + (size_t)(bn + 64 + wave * 16 + r_a) * ldw + k8;

    const int wm = (wave & 1) * 64;
    const int wn = (wave >> 1) * 64;
    const int lr = lane & 15;
    const int quad = lane >> 4;

    f32x4 acc[4][4];
    const f32x4 zero = {0.f, 0.f, 0.f, 0.f};
#pragma unroll
    for (int i = 0; i < 4; i++)
#pragma unroll
        for (int j = 0; j < 4; j++) acc[i][j] = zero;

#define STAGE(koff, j) do { \
        gload16(gA0 + (koff), As[j] + wave * 512); \
        gload16(gA1 + (koff), As[j] + (wave + 4) * 512); \
        gload16(gB0 + (koff), Bs[j] + wave * 512); \
        gload16(gB1 + (koff), Bs[j] + (wave + 4) * 512); \
    } while (0)

    const int niter = Kc >> 5;
    STAGE(0, 0);
    if (niter > 1) STAGE(32, 1);

    int ib = 0;   // LDS buffer holding tile k
    for (int k = 0; k < niter; k++) {
        if (k + 1 < niter)
            asm volatile("s_waitcnt vmcnt(4)\n\ts_barrier" ::: "memory");
        else
            asm volatile("s_waitcnt vmcnt(0)\n\ts_barrier" ::: "memory");
        if (k + 2 < niter) {
            int is_ = ib + 2; if (is_ >= 3) is_ -= 3;
            STAGE((k + 2) << 5, is_);
        }
        const unsigned short* as = As[ib];
        const unsigned short* bs = Bs[ib];
        bf16x8 fa[4], fb[4];
#pragma unroll
        for (int mi = 0; mi < 4; mi++)
            fa[mi] = *reinterpret_cast<const bf16x8*>(as + (wm + mi * 16 + lr) * 32 + quad * 8);
#pragma unroll
        for (int ni = 0; ni < 4; ni++)
            fb[ni] = *reinterpret_cast<const bf16x8*>(bs + (wn + ni * 16 + lr) * 32 + quad * 8);
#pragma unroll
        for (int mi = 0; mi < 4; mi++)
#pragma unroll
            for (int ni = 0; ni < 4; ni++)
                acc[mi][ni] = __builtin_amdgcn_mfma_f32_16x16x32_bf16(fa[mi], fb[ni], acc[mi][ni], 0, 0, 0);
        ib = (ib == 2) ? 0 : ib + 1;
    }
#undef STAGE

    // C/D layout: col = lane&15 (+16*ni), row = quad*4 + reg (+16*mi)
#pragma unroll
    for (int mi = 0; mi < 4; mi++)
#pragma unroll
        for (int reg = 0; reg < 4; reg++) {
            int row = bm + wm + mi * 16 + quad * 4 + reg;
#pragma unroll
            for (int ni = 0; ni < 4; ni++) {
                int col = bn + wn + ni * 16 + lr;
                float v = acc[mi][ni][reg];
                if (OP == 0) {
                    float* Cf = (float*)Cout + (size_t)kz * czs;
                    Cf[(size_t)row * ldc + col] = v;
                } else if (OP == 2) {
                    if (col >= silu_col0) v = silu_f(v);
                    ((unsigned short*)Cout)[(size_t)row * ldc + col] = f2b(v);
                } else {  // OP == 3
                    ((unsigned short*)Cout)[(size_t)row * ldc + col] = f2b(softplus_f(v + bias[col]));
                }
            }
        }
}

// ---------- split-K reduction for x_proj; fuses dtin bf16 extraction ----------
__global__ __launch_bounds__(256)
void reduce_xpart(const float* __restrict__ xpart, float* __restrict__ ssmp,
                  unsigned short* __restrict__ dtin) {
    const int BL = 4096;
    int idx = blockIdx.x * 256 + threadIdx.x;   // BL*32 threads
    int row = idx >> 5;
    int c4 = (idx & 31) * 4;
    float4 s = {0.f, 0.f, 0.f, 0.f};
#pragma unroll
    for (int z = 0; z < 8; z++) {
        float4 v = *reinterpret_cast<const float4*>(xpart + (size_t)z * BL * 128 + (size_t)row * 128 + c4);
        s.x += v.x; s.y += v.y; s.z += v.z; s.w += v.w;
    }
    *reinterpret_cast<float4*>(ssmp + (size_t)row * 128 + c4) = s;
    if (c4 < 96) {
        ushort4 o;
        o.x = f2b(s.x); o.y = f2b(s.y); o.z = f2b(s.z); o.w = f2b(s.w);
        *reinterpret_cast<ushort4*>(dtin + (size_t)row * 96 + c4) = o;
    }
}

// ---------- causal depthwise conv (K=4) + SiLU, 8 channels/thread ----------
__global__ __launch_bounds__(256)
void conv_silu8(const unsigned short* __restrict__ projbf, const float* __restrict__ cw,
                const float* __restrict__ cb, unsigned short* __restrict__ xc) {
    const int I = 3072, L = 2048, LD = 6144;
    int idx = blockIdx.x * 256 + threadIdx.x;    // over BL*I/8
    int i8 = (idx % (I / 8)) * 8;
    int bl = idx / (I / 8);
    int l = bl & (L - 1);
    float s[8];
    {
        float4 b0 = *reinterpret_cast<const float4*>(cb + i8);
        float4 b1 = *reinterpret_cast<const float4*>(cb + i8 + 4);
        s[0]=b0.x; s[1]=b0.y; s[2]=b0.z; s[3]=b0.w; s[4]=b1.x; s[5]=b1.y; s[6]=b1.z; s[7]=b1.w;
    }
    float w[8][4];
#pragma unroll
    for (int c = 0; c < 8; c++) {
        float4 wr = *reinterpret_cast<const float4*>(cw + (i8 + c) * 4);
        w[c][0]=wr.x; w[c][1]=wr.y; w[c][2]=wr.z; w[c][3]=wr.w;
    }
#pragma unroll
    for (int j = 0; j < 4; j++) {
        if (l + j - 3 >= 0) {
            uint4 r = *reinterpret_cast<const uint4*>(projbf + (size_t)(bl + j - 3) * LD + i8);
            float xv[8];
            xv[0]=b2f((unsigned short)(r.x & 0xffff)); xv[1]=b2f((unsigned short)(r.x >> 16));
            xv[2]=b2f((unsigned short)(r.y & 0xffff)); xv[3]=b2f((unsigned short)(r.y >> 16));
            xv[4]=b2f((unsigned short)(r.z & 0xffff)); xv[5]=b2f((unsigned short)(r.z >> 16));
            xv[6]=b2f((unsigned short)(r.w & 0xffff)); xv[7]=b2f((unsigned short)(r.w >> 16));
#pragma unroll
            for (int c = 0; c < 8; c++) s[c] = fmaf(xv[c], w[c][j], s[c]);
        }
    }
    unsigned short o[8];
#pragma unroll
    for (int c = 0; c < 8; c++) o[c] = f2b(silu_f(s[c]));
    uint4 packed;
    packed.x = (unsigned)o[0] | ((unsigned)o[1] << 16);
    packed.y = (unsigned)o[2] | ((unsigned)o[3] << 16);
    packed.z = (unsigned)o[4] | ((unsigned)o[5] << 16);
    packed.w = (unsigned)o[6] | ((unsigned)o[7] << 16);
    *reinterpret_cast<uint4*>(xc + (size_t)bl * I + i8) = packed;
}

// ---------- pass A: per-chunk local scan (init 0) -> S_local, sumDelta ----------
__global__ __launch_bounds__(256)
void scan_passA(const unsigned short* __restrict__ delta_bf, const unsigned short* __restrict__ xc,
                const float* __restrict__ ssmp, const float* __restrict__ Aw,
                float* __restrict__ S_local, float* __restrict__ sumDelta) {
    const int I = 3072, L = 2048;
    __shared__ float bc[TCH][32];
    int g = blockIdx.x * 256 + threadIdx.x;
    int i = g % I;
    int bcid = g / I;
    int c = bcid % CCH;
    int b = bcid / CCH;
    size_t rowbase = (size_t)b * L + (size_t)c * TCH;
    for (int e = threadIdx.x; e < TCH * 8; e += 256) {
        int t = e >> 3, q = e & 7;
        float4 v = *reinterpret_cast<const float4*>(ssmp + (rowbase + t) * 128 + 96 + q * 4);
        *reinterpret_cast<float4*>(&bc[t][q * 4]) = v;
    }
    __syncthreads();

    float Arow[16];
#pragma unroll
    for (int n = 0; n < 16; n++) Arow[n] = Aw[i * 16 + n];
    float st[16];
#pragma unroll
    for (int n = 0; n < 16; n++) st[n] = 0.f;
    float sumD = 0.f;

    size_t rowI = rowbase * I + i;
    for (int t = 0; t < TCH; t++) {
        float delta = b2f(delta_bf[rowI]);
        float du = delta * b2f(xc[rowI]);
        sumD += delta;
        float4 b0 = *reinterpret_cast<const float4*>(&bc[t][0]);
        float4 b1 = *reinterpret_cast<const float4*>(&bc[t][4]);
        float4 b2 = *reinterpret_cast<const float4*>(&bc[t][8]);
        float4 b3 = *reinterpret_cast<const float4*>(&bc[t][12]);
        const float bv[16] = {b0.x,b0.y,b0.z,b0.w, b1.x,b1.y,b1.z,b1.w,
                              b2.x,b2.y,b2.z,b2.w, b3.x,b3.y,b3.z,b3.w};
#pragma unroll
        for (int n = 0; n < 16; n++)
            st[n] = fmaf(st[n], __expf(delta * Arow[n]), du * bv[n]);
        rowI += I;
    }
    size_t obase = (size_t)bcid * 16 * I + i;
#pragma unroll
    for (int n = 0; n < 16; n++) S_local[obase + (size_t)n * I] = st[n];
    sumDelta[(size_t)bcid * I + i] = sumD;
}

// ---------- pass B: sequential combine across chunks -> state_in ----------
__global__ __launch_bounds__(256)
void scan_passB(const float* __restrict__ S_local, const float* __restrict__ sumDelta,
                const float* __restrict__ Aw, float* __restrict__ state_in) {
    const int I = 3072;
    int g = blockIdx.x * 256 + threadIdx.x;
    int i = g % I;
    int bn = g / I;
    int n = bn & 15;
    int b = bn >> 4;
    float a = Aw[i * 16 + n];
    float state = 0.f;
    for (int c = 0; c < CCH; c++) {
        int bcid = b * CCH + c;
        size_t idx = ((size_t)bcid * 16 + n) * I + i;
        state_in[idx] = state;
        state = fmaf(state, __expf(a * sumDelta[(size_t)bcid * I + i]), S_local[idx]);
    }
}

// ---------- pass C: re-scan from state_in; fused y, D-skip, pre-silu'd gate ----------
__global__ __launch_bounds__(256)
void scan_passC(const unsigned short* __restrict__ projbf,   // silu(gate) at col 3072+i, ld 6144
                const unsigned short* __restrict__ xc,
                const float* __restrict__ ssmp, const unsigned short* __restrict__ delta_bf,
                const float* __restrict__ Aw, const float* __restrict__ Dw,
                const float* __restrict__ state_in, unsigned short* __restrict__ ybf) {
    const int I = 3072, L = 2048, LD = 6144;
    __shared__ float bc[TCH][32];
    int g = blockIdx.x * 256 + threadIdx.x;
    int i = g % I;
    int bcid = g / I;
    int c = bcid % CCH;
    int b = bcid / CCH;
    size_t rowbase = (size_t)b * L + (size_t)c * TCH;
    for (int e = threadIdx.x; e < TCH * 8; e += 256) {
        int t = e >> 3, q = e & 7;
        float4 v = *reinterpret_cast<const float4*>(ssmp + (rowbase + t) * 128 + 96 + q * 4);
        *reinterpret_cast<float4*>(&bc[t][q * 4]) = v;
    }
    __syncthreads();

    float Arow[16];
#pragma unroll
    for (int n = 0; n < 16; n++) Arow[n] = Aw[i * 16 + n];
    float Dv = Dw[i];
    float st[16];
    size_t sbase = (size_t)bcid * 16 * I + i;
#pragma unroll
    for (int n = 0; n < 16; n++) st[n] = state_in[sbase + (size_t)n * I];

    size_t rowI = rowbase * I + i;
    size_t rowG = rowbase * LD + I + i;
    for (int t = 0; t < TCH; t++) {
        float delta = b2f(delta_bf[rowI]);
        float u = b2f(xc[rowI]);
        float du = delta * u;
        float4 b0 = *reinterpret_cast<const float4*>(&bc[t][0]);
        float4 b1 = *reinterpret_cast<const float4*>(&bc[t][4]);
        float4 b2 = *reinterpret_cast<const float4*>(&bc[t][8]);
        float4 b3 = *reinterpret_cast<const float4*>(&bc[t][12]);
        float4 c0 = *reinterpret_cast<const float4*>(&bc[t][16]);
        float4 c1 = *reinterpret_cast<const float4*>(&bc[t][20]);
        float4 c2 = *reinterpret_cast<const float4*>(&bc[t][24]);
        float4 c3 = *reinterpret_cast<const float4*>(&bc[t][28]);
        const float bv[16] = {b0.x,b0.y,b0.z,b0.w, b1.x,b1.y,b1.z,b1.w,
                              b2.x,b2.y,b2.z,b2.w, b3.x,b3.y,b3.z,b3.w};
        const float cv[16] = {c0.x,c0.y,c0.z,c0.w, c1.x,c1.y,c1.z,c1.w,
                              c2.x,c2.y,c2.z,c2.w, c3.x,c3.y,c3.z,c3.w};
        float y = 0.f;
#pragma unroll
        for (int n = 0; n < 16; n++) {
            st[n] = fmaf(st[n], __expf(delta * Arow[n]), du * bv[n]);
            y = fmaf(st[n], cv[n], y);
        }
        y = fmaf(u, Dv, y);
        y *= b2f(projbf[rowG]);            // gate already silu'd in GEMM epilogue
        ybf[rowI] = f2b(y);
        rowI += I;
        rowG += LD;
    }
}

extern "C" void kernel_launch(void* const* d_in, const int* in_sizes, int n_in,
                              void* d_out, int out_size, void* d_ws, size_t ws_size,
                              hipStream_t stream) {
    const float* hidden  = (const float*)d_in[0];
    const float* W_in    = (const float*)d_in[1];
    const float* conv_w  = (const float*)d_in[2];
    const float* conv_b  = (const float*)d_in[3];
    const float* W_x     = (const float*)d_in[4];
    const float* W_dt    = (const float*)d_in[5];
    const float* dt_bias = (const float*)d_in[6];
    const float* Aw      = (const float*)d_in[7];
    const float* Dw      = (const float*)d_in[8];
    const float* W_out   = (const float*)d_in[9];
    float* out = (float*)d_out;

    constexpr int Bsz = 2, L = 2048, H = 1536, I = 3072, R = 96;
    constexpr int BL = Bsz * L;        // 4096
    constexpr int TwoI = 2 * I;        // 6144

    // ---- workspace layout ----
    char* base = (char*)d_ws;
    unsigned short* proj_bf  = (unsigned short*)base; base += (size_t)BL * TwoI * 2;   // 50.3 MB
    unsigned short* delta_bf = (unsigned short*)base; base += (size_t)BL * I * 2;      // 25.2 MB
    unsigned short* xc_bf    = (unsigned short*)base; base += (size_t)BL * I * 2;      // 25.2 MB
    unsigned short* y_bf     = (unsigned short*)base; base += (size_t)BL * I * 2;      // 25.2 MB
    float* ssmp              = (float*)base;          base += (size_t)BL * 128 * 4;    // 2.1 MB
    float* xpart             = (float*)base;          base += (size_t)8 * BL * 128 * 4;// 16.8 MB
    unsigned short* dtin_bf  = (unsigned short*)base; base += (size_t)BL * R * 2;      // 0.8 MB
    unsigned short* wx_bf    = (unsigned short*)base; base += (size_t)128 * I * 2;     // 0.8 MB
    unsigned short* wdt_bf   = (unsigned short*)base; base += (size_t)I * R * 2;       // 0.6 MB
    unsigned short* wout_bf  = (unsigned short*)base; base += (size_t)H * I * 2;       // 9.4 MB
    unsigned short* h_bf     = (unsigned short*)base; base += (size_t)BL * H * 2;      // 12.6 MB
    unsigned short* win_bf   = (unsigned short*)base; base += (size_t)TwoI * H * 2;    // 18.9 MB
    // scan scratch overlays h_bf+win_bf (dead after in_proj): 26.0 <= 31.5 MB
    float* S_local  = (float*)h_bf;
    float* sumDelta = S_local + (size_t)Bsz * CCH * 16 * I;
    float* state_in = sumDelta + (size_t)Bsz * CCH * I;

    dim3 blk(256);

    // 0) fused weight/act casts
    cast_all<<<(5283840 + 255) / 256, blk, 0, stream>>>(
        hidden, W_in, W_x, W_dt, W_out, h_bf, win_bf, wx_bf, wdt_bf, wout_bf);

    // 1) in_proj -> proj_bf [4096,6144] bf16; silu on gate half (cols >= 3072)
    //    256^2 8-phase (r1, measured best): grid 384 (%8==0)
    gemm256<2><<<dim3(24 * 16, 1, 1), dim3(512), 0, stream>>>(
        h_bf, win_bf, proj_bf, H, H, H, TwoI, /*ntx*/ TwoI / 256, /*silu*/ I, 0);

    // 2) causal conv + SiLU -> xc_bf
    conv_silu8<<<BL * I / 8 / 256, blk, 0, stream>>>(proj_bf, conv_w, conv_b, xc_bf);

    // 3) x_proj split-K x8: xpart[z][4096][128] = xc @ wx^T (K chunk 384)
    gemm_mfma<0><<<dim3(1, BL / 128, 8), blk, 0, stream>>>(
        xc_bf, wx_bf, xpart, I / 8, I, I, 128, nullptr, 0, (long long)BL * 128);
    reduce_xpart<<<BL * 32 / 256, blk, 0, stream>>>(xpart, ssmp, dtin_bf);

    // 4) dt_proj, fused +bias & softplus -> delta_bf [4096,3072] bf16
    gemm_mfma<3><<<dim3(I / 128, BL / 128, 1), blk, 0, stream>>>(
        dtin_bf, wdt_bf, delta_bf, R, R, R, I, dt_bias, 0, 0);

    // 5) chunk-parallel selective scan
    scan_passA<<<Bsz * I * CCH / 256, blk, 0, stream>>>(
        delta_bf, xc_bf, ssmp, Aw, S_local, sumDelta);
    scan_passB<<<Bsz * 16 * I / 256, blk, 0, stream>>>(
        S_local, sumDelta, Aw, state_in);
    scan_passC<<<Bsz * I * CCH / 256, blk, 0, stream>>>(
        proj_bf, xc_bf, ssmp, delta_bf, Aw, Dw, state_in, y_bf);

    // 6) out_proj: 128x192 tiles, grid EXACTLY 256 blocks (one full round),
    //    K=3072 single pass, fp32 direct to out
    gemm_out<<<dim3(256, 1, 1), dim3(512), 0, stream>>>(
        y_bf, wout_bf, out, I, I, I, H);
}